// Round 1
// baseline (162.855 us; speedup 1.0000x reference)
//
#include <hip/hip_runtime.h>
#include <hip/hip_bf16.h>
#include <stdint.h>

#define BB 16
#define CC 128
#define HH 64
#define WW 64
#define LL 4096
#define SS 16
#define NCH 64
#define CT 64

typedef __attribute__((ext_vector_type(4))) float f32x4;
typedef __attribute__((ext_vector_type(8))) short short8;
typedef __attribute__((ext_vector_type(4))) unsigned int u32x4;

#define AS1 __attribute__((address_space(1)))
#define AS3 __attribute__((address_space(3)))

__device__ __forceinline__ float bf2f(unsigned short u) {
    union { unsigned int i; float f; } v;
    v.i = ((unsigned int)u) << 16;
    return v.f;
}
__device__ __forceinline__ unsigned short f2bf(float f) {
    union { float f; unsigned int i; } v;
    v.f = f;
    unsigned int x = v.i;
    return (unsigned short)((x + 0x7fffu + ((x >> 16) & 1u)) >> 16);
}
__device__ __forceinline__ float fexp2(float x) { return __builtin_amdgcn_exp2f(x); }

// ---------------- K0a: weight fragment transforms + An/Dp tables ----------------
__global__ void k0a(const float* __restrict__ conv_w, const float* __restrict__ dt_w,
                    const float* __restrict__ A, const float* __restrict__ Dv,
                    short* __restrict__ wf, short* __restrict__ wdtf,
                    float* __restrict__ An, float* __restrict__ An2, float* __restrict__ Dp) {
    int idx = blockIdx.x * 256 + threadIdx.x;
    if (idx < 18432) {
        // conv weight frags: frag fr = ((tp*4+ks)*8+nfg), value B[k=cin][n=cout]
        int lane = idx & 63, fr = idx >> 6;
        int nfg = fr & 7, ks = (fr >> 3) & 3, tp = fr >> 5;
        int dy = tp / 3, dx = tp % 3;
        int cout = nfg * 16 + (lane & 15);
        int cin0 = ks * 32 + (lane >> 4) * 8;
        short8 v;
#pragma unroll
        for (int j = 0; j < 8; ++j)
            v[j] = (short)f2bf(conv_w[((cout * CC + cin0 + j) * 3 + dy) * 3 + dx]);
        *(short8*)(wf + (size_t)idx * 8) = v;
    } else if (idx < 20480) {
        int i2 = idx - 18432;
        int lane = i2 & 63, fr = i2 >> 6;
        int nfg = fr & 7, ks = fr >> 3;
        int o = nfg * 16 + (lane & 15);
        int c0 = ks * 32 + (lane >> 4) * 8;
        short8 v;
#pragma unroll
        for (int j = 0; j < 8; ++j) v[j] = (short)f2bf(dt_w[o * CC + c0 + j]);
        *(short8*)(wdtf + (size_t)i2 * 8) = v;
    } else if (idx < 22528) {
        int i3 = idx - 20480;
        float a = -expf(A[i3]);
        An[i3] = a;
        An2[i3] = a * 1.4426950408889634f;
    } else if (idx < 22656) {
        int c = idx - 22528;
        Dp[c] = expf(Dv[c]);
    }
}

// ---------------- K0b: transpose x[b][c][t] -> xT[b][t][c] (bf16) ----------------
__global__ __launch_bounds__(256) void k0b(const float* __restrict__ x, unsigned short* __restrict__ xT) {
    __shared__ float lt[64][65];
    int bid = blockIdx.x;             // 2048
    int b = bid >> 7, rem = bid & 127;
    int tt = rem >> 1, ct = rem & 1;
    int t0 = tt * 64, c0 = ct * 64;
    int tid = threadIdx.x;
    int colr = tid & 63, rowb = tid >> 6;  // rowb 0..3
#pragma unroll
    for (int r = 0; r < 16; ++r) {
        int row = rowb + r * 4;  // c-local
        lt[row][colr] = x[(size_t)(b * CC + c0 + row) * LL + t0 + colr];
    }
    __syncthreads();
#pragma unroll
    for (int r = 0; r < 16; ++r) {
        int trow = rowb + r * 4;  // t-local
        xT[((size_t)b * LL + t0 + trow) * CC + c0 + colr] = f2bf(lt[colr][trow]);
    }
}

// ---------------- K1: 3x3 conv via MFMA implicit GEMM ----------------
__global__ __launch_bounds__(256) void k1(const unsigned short* __restrict__ xT,
                                          const short* __restrict__ wf,
                                          const float* __restrict__ conv_b,
                                          unsigned short* __restrict__ convT,
                                          float* __restrict__ pooled) {
    __shared__ __align__(16) unsigned short slab[3 * 66 * 128];  // 50688 B
    int bid = blockIdx.x;
    int b = bid >> 6, h = bid & 63;
    int tid = threadIdx.x;
    int wave = tid >> 6, lane = tid & 63;

    // zero halo rows (tok 0 and tok 65 of each dy): 3*2*256B
    if (tid < 96) {
        int dy = tid >> 5, r = (tid >> 4) & 1, j = tid & 15;
        u32x4 z = {0, 0, 0, 0};
        *(u32x4*)((char*)slab + dy * 16896 + (r ? 16640 : 0) + j * 16) = z;
    }
#pragma unroll
    for (int dy = 0; dy < 3; ++dy) {
        int hs = h + dy - 1;
        char* slabdy = (char*)slab + dy * 16896;
        if (hs >= 0 && hs < HH) {
            const char* src = (const char*)xT + (size_t)(b * LL + hs * 64) * 256;
#pragma unroll
            for (int i = 0; i < 4; ++i) {
                unsigned int Xbase = 256u + (unsigned)i * 4096u + (unsigned)wave * 1024u;
                unsigned int X = Xbase + (unsigned)lane * 16u;
                unsigned int tok = X >> 8;
                unsigned int srcoff = ((X & ~255u) - 256u) | ((X & 255u) ^ ((tok & 7u) << 4));
                __builtin_amdgcn_global_load_lds((const AS1 unsigned int*)(src + srcoff),
                                                 (AS3 unsigned int*)(slabdy + Xbase), 16, 0, 0);
            }
        } else {
            u32x4 z = {0, 0, 0, 0};
#pragma unroll
            for (int i = 0; i < 4; ++i)
                *(u32x4*)(slabdy + 256 + tid * 64 + i * 16) = z;
        }
    }
    __syncthreads();

    int lm = lane & 15, lg = lane >> 4;
    f32x4 acc[4][2];
#pragma unroll
    for (int m = 0; m < 4; ++m)
#pragma unroll
        for (int n = 0; n < 2; ++n) acc[m][n] = (f32x4){0.f, 0.f, 0.f, 0.f};

#pragma unroll
    for (int tp = 0; tp < 9; ++tp) {
        int dy = tp / 3, dx = tp % 3;
        const char* slabdy = (const char*)slab + dy * 16896;
#pragma unroll
        for (int ks = 0; ks < 4; ++ks) {
            short8 bf0 = *(const short8*)(wf + ((size_t)(((tp * 4 + ks) * 8) + wave * 2 + 0) * 64 + lane) * 8);
            short8 bf1 = *(const short8*)(wf + ((size_t)(((tp * 4 + ks) * 8) + wave * 2 + 1) * 64 + lane) * 8);
#pragma unroll
            for (int mf = 0; mf < 4; ++mf) {
                int tok = mf * 16 + lm + dx;
                unsigned int off = (unsigned)((tok * 256 + ks * 64 + lg * 16) ^ ((tok & 7) << 4));
                short8 af = *(const short8*)(slabdy + off);
                acc[mf][0] = __builtin_amdgcn_mfma_f32_16x16x32_bf16(af, bf0, acc[mf][0], 0, 0, 0);
                acc[mf][1] = __builtin_amdgcn_mfma_f32_16x16x32_bf16(af, bf1, acc[mf][1], 0, 0, 0);
            }
        }
    }

    // epilogue: bias, write convT bf16, pooling partials
    int n0w = wave * 32;
    size_t tokbase = (size_t)(b * LL + h * 64);
    float psum[2] = {0.f, 0.f};
#pragma unroll
    for (int nf = 0; nf < 2; ++nf) {
        int n = n0w + nf * 16 + lm;
        float bias = conv_b[n];
#pragma unroll
        for (int mf = 0; mf < 4; ++mf)
#pragma unroll
            for (int r = 0; r < 4; ++r) {
                int w = mf * 16 + lg * 4 + r;
                float v = acc[mf][nf][r] + bias;
                convT[(tokbase + w) * CC + n] = f2bf(v);
                psum[nf] += v;
            }
    }
#pragma unroll
    for (int nf = 0; nf < 2; ++nf) {
        float s = psum[nf];
        s += __shfl_xor(s, 16);
        s += __shfl_xor(s, 32);
        if (lane < 16) atomicAdd(&pooled[b * CC + n0w + nf * 16 + lane], s);
    }
}

// ---------------- K2: spectral gate ----------------
__global__ __launch_bounds__(128) void k2(const float* __restrict__ pooled, const float* __restrict__ g1w,
                                          const float* __restrict__ g1b, const float* __restrict__ g2w,
                                          const float* __restrict__ g2b, float* __restrict__ gate) {
    __shared__ float wl[128 * 129];
    __shared__ float meanr[128];
    __shared__ float garr[128];
    int b = blockIdx.x;
    int tid = threadIdx.x;  // 128
    meanr[tid] = pooled[b * CC + tid] * (1.f / 4096.f);
#pragma unroll 4
    for (int i = 0; i < 128; ++i) wl[i * 129 + tid] = g1w[i * 128 + tid];
    __syncthreads();
    float acc = g1b[tid];
    for (int c = 0; c < 128; ++c) acc += meanr[c] * wl[tid * 129 + c];
    garr[tid] = fmaxf(acc, 0.f);
    __syncthreads();
#pragma unroll 4
    for (int i = 0; i < 128; ++i) wl[i * 129 + tid] = g2w[i * 128 + tid];
    __syncthreads();
    float acc2 = g2b[tid];
    for (int c = 0; c < 128; ++c) acc2 += garr[c] * wl[tid * 129 + c];
    gate[b * CC + tid] = __builtin_amdgcn_rcpf(1.f + fexp2(-1.4426950408889634f * acc2));
}

// ---------------- K3: dt = sigmoid((convT*gate) @ dt_w^T + dt_b) ----------------
__global__ __launch_bounds__(256) void k3(const unsigned short* __restrict__ convT,
                                          const short* __restrict__ wdtf,
                                          const float* __restrict__ gate,
                                          const float* __restrict__ dt_b,
                                          unsigned short* __restrict__ dtT) {
    __shared__ __align__(16) unsigned short albuf[128 * 128];  // 32KB
    __shared__ float gl[128];
    int bid = blockIdx.x;
    int b = bid >> 5, t0 = (bid & 31) * 128;
    int tid = threadIdx.x;
    int wave = tid >> 6, lane = tid & 63;
    if (tid < 128) gl[tid] = gate[b * CC + tid];
    __syncthreads();
    const char* srcb = (const char*)convT + (size_t)(b * LL + t0) * 256;
#pragma unroll
    for (int i = 0; i < 8; ++i) {
        unsigned int byteoff = (unsigned)((i * 256 + tid) * 16);
        unsigned int tok = byteoff >> 8;
        unsigned int inner = byteoff & 255u;
        int c8 = (int)(inner >> 1);
        short8 v = *(const short8*)(srcb + (size_t)tok * 256 + inner);
#pragma unroll
        for (int j = 0; j < 8; ++j) {
            float f = bf2f((unsigned short)v[j]) * gl[c8 + j];
            v[j] = (short)f2bf(f);
        }
        *(short8*)((char*)albuf + (byteoff ^ ((tok & 7u) << 4))) = v;
    }
    __syncthreads();

    int lm = lane & 15, lg = lane >> 4;
    f32x4 acc[8][2];
#pragma unroll
    for (int m = 0; m < 8; ++m)
#pragma unroll
        for (int n = 0; n < 2; ++n) acc[m][n] = (f32x4){0.f, 0.f, 0.f, 0.f};
#pragma unroll
    for (int ks = 0; ks < 4; ++ks) {
        short8 bf0 = *(const short8*)(wdtf + ((size_t)((ks * 8) + wave * 2 + 0) * 64 + lane) * 8);
        short8 bf1 = *(const short8*)(wdtf + ((size_t)((ks * 8) + wave * 2 + 1) * 64 + lane) * 8);
#pragma unroll
        for (int mf = 0; mf < 8; ++mf) {
            int tok = mf * 16 + lm;
            unsigned int off = (unsigned)((tok * 256 + ks * 64 + lg * 16) ^ ((tok & 7) << 4));
            short8 af = *(const short8*)((const char*)albuf + off);
            acc[mf][0] = __builtin_amdgcn_mfma_f32_16x16x32_bf16(af, bf0, acc[mf][0], 0, 0, 0);
            acc[mf][1] = __builtin_amdgcn_mfma_f32_16x16x32_bf16(af, bf1, acc[mf][1], 0, 0, 0);
        }
    }
#pragma unroll
    for (int nf = 0; nf < 2; ++nf) {
        int o = wave * 32 + nf * 16 + lm;
        float zb = dt_b[o];
#pragma unroll
        for (int mf = 0; mf < 8; ++mf)
#pragma unroll
            for (int r = 0; r < 4; ++r) {
                int tok = mf * 16 + lg * 4 + r;
                float z = acc[mf][nf][r] + zb;
                float d = __builtin_amdgcn_rcpf(1.f + fexp2(-1.4426950408889634f * z));
                dtT[(size_t)(b * LL + t0 + tok) * CC + o] = f2bf(d);
            }
    }
}

// ---------------- K4: scan phase 1 (local chunk states + decay) ----------------
__global__ __launch_bounds__(128) void k4(const unsigned short* __restrict__ convT,
                                          const unsigned short* __restrict__ dtT,
                                          const float* __restrict__ gate,
                                          const float* __restrict__ An2,
                                          float* __restrict__ hend, float* __restrict__ decay) {
    int bid = blockIdx.x;
    int b = bid >> 6, ch = bid & 63;
    int c = threadIdx.x;
    float a2[SS], h[SS];
#pragma unroll
    for (int s = 0; s < SS; ++s) {
        a2[s] = An2[c * SS + s];
        h[s] = 0.f;
    }
    float g = gate[b * CC + c];
    float sdt = 0.f;
    int t0 = ch * CT;
    const unsigned short* xp = convT + (size_t)(b * LL + t0) * CC + c;
    const unsigned short* dp = dtT + (size_t)(b * LL + t0) * CC + c;
#pragma unroll 4
    for (int t = 0; t < CT; ++t) {
        float x = bf2f(xp[t * CC]) * g;
        float d = bf2f(dp[t * CC]);
        sdt += d;
#pragma unroll
        for (int s = 0; s < SS; ++s) h[s] = h[s] * fexp2(a2[s] * d) + x;
    }
    size_t base = ((size_t)(b * NCH + ch) * CC + c) * SS;
#pragma unroll
    for (int s = 0; s < SS; ++s) {
        hend[base + s] = h[s];
        decay[base + s] = fexp2(a2[s] * sdt);
    }
}

// ---------------- K5: sequential chunk combine ----------------
__global__ __launch_bounds__(256) void k5(const float* __restrict__ hend, const float* __restrict__ decay,
                                          float* __restrict__ H0) {
    int idx = blockIdx.x * 256 + threadIdx.x;  // 32768
    int b = idx >> 11, rem = idx & 2047;
    float Hv = 0.f;
    for (int k = 0; k < NCH; ++k) {
        size_t base = (size_t)(b * NCH + k) * 2048 + rem;
        H0[base] = Hv;
        Hv = hend[base] + Hv * decay[base];
    }
}

// ---------------- K6: scan phase 2 (emit y + identity) ----------------
__global__ __launch_bounds__(128) void k6(const unsigned short* __restrict__ convT,
                                          const unsigned short* __restrict__ dtT,
                                          const float* __restrict__ gate,
                                          const float* __restrict__ Antab,
                                          const float* __restrict__ An2tab,
                                          const float* __restrict__ Dp,
                                          const float* __restrict__ H0,
                                          const float* __restrict__ xin,
                                          float* __restrict__ out) {
    int bid = blockIdx.x;
    int b = bid >> 6, ch = bid & 63;
    int c = threadIdx.x;
    float a2[SS], an[SS], h[SS];
#pragma unroll
    for (int s = 0; s < SS; ++s) {
        a2[s] = An2tab[c * SS + s];
        an[s] = Antab[c * SS + s];
    }
    size_t hbase = ((size_t)(b * NCH + ch) * CC + c) * SS;
#pragma unroll
    for (int s = 0; s < SS; ++s) h[s] = H0[hbase + s];
    float g = gate[b * CC + c];
    float dpc = Dp[c];
    int t0 = ch * CT;
    const unsigned short* xp = convT + (size_t)(b * LL + t0) * CC + c;
    const unsigned short* dp = dtT + (size_t)(b * LL + t0) * CC + c;
    const float* idp = xin + (size_t)(b * CC + c) * LL + t0;
    float* op = out + (size_t)(b * CC + c) * LL + t0;
    for (int tt = 0; tt < CT; tt += 4) {
        f32x4 id4 = *(const f32x4*)(idp + tt);
        f32x4 y4;
#pragma unroll
        for (int u = 0; u < 4; ++u) {
            int t = tt + u;
            float x = bf2f(xp[t * CC]) * g;
            float d = bf2f(dp[t * CC]);
            float y = dpc * x;
#pragma unroll
            for (int s = 0; s < SS; ++s) {
                h[s] = h[s] * fexp2(a2[s] * d) + x;
                y += h[s] * an[s];
            }
            y4[u] = y + id4[u];
        }
        *(f32x4*)(op + tt) = y4;
    }
}

extern "C" void kernel_launch(void* const* d_in, const int* in_sizes, int n_in,
                              void* d_out, int out_size, void* d_ws, size_t ws_size,
                              hipStream_t stream) {
    const float* x      = (const float*)d_in[0];
    const float* conv_w = (const float*)d_in[1];
    const float* conv_b = (const float*)d_in[2];
    const float* dt_w   = (const float*)d_in[3];
    const float* dt_b   = (const float*)d_in[4];
    const float* A      = (const float*)d_in[5];
    const float* D      = (const float*)d_in[6];
    const float* g1w    = (const float*)d_in[7];
    const float* g1b    = (const float*)d_in[8];
    const float* g2w    = (const float*)d_in[9];
    const float* g2b    = (const float*)d_in[10];

    char* ws = (char*)d_ws;
    // layout (xT overlaid by hend/decay after K1's last read of xT)
    unsigned short* xT    = (unsigned short*)(ws + 0);          // 16.78 MB
    float* hend           = (float*)(ws + 0);                   //  8.39 MB (after K1)
    float* decay          = (float*)(ws + 8388608);             //  8.39 MB
    unsigned short* convT = (unsigned short*)(ws + 16777216);   // 16.78 MB
    unsigned short* dtT   = (unsigned short*)(ws + 33554432);   // 16.78 MB
    float* H0             = (float*)(ws + 50331648);            //  8.39 MB
    short* wf             = (short*)(ws + 58720256);            //  294912 B
    short* wdtf           = (short*)(ws + 59015168);            //  32768 B
    float* pooled         = (float*)(ws + 59047936);            //  8192 B
    float* gate           = (float*)(ws + 59056128);            //  8192 B
    float* Antab          = (float*)(ws + 59064320);            //  8192 B
    float* An2tab         = (float*)(ws + 59072512);            //  8192 B
    float* Dp             = (float*)(ws + 59080704);            //  512 B
    float* outp           = (float*)d_out;

    hipMemsetAsync(pooled, 0, BB * CC * sizeof(float), stream);
    hipLaunchKernelGGL(k0a, dim3(89), dim3(256), 0, stream, conv_w, dt_w, A, D, wf, wdtf, Antab, An2tab, Dp);
    hipLaunchKernelGGL(k0b, dim3(2048), dim3(256), 0, stream, x, xT);
    hipLaunchKernelGGL(k1, dim3(1024), dim3(256), 0, stream, xT, wf, conv_b, convT, pooled);
    hipLaunchKernelGGL(k2, dim3(16), dim3(128), 0, stream, pooled, g1w, g1b, g2w, g2b, gate);
    hipLaunchKernelGGL(k3, dim3(512), dim3(256), 0, stream, convT, wdtf, gate, dt_b, dtT);
    hipLaunchKernelGGL(k4, dim3(1024), dim3(128), 0, stream, convT, dtT, gate, An2tab, hend, decay);
    hipLaunchKernelGGL(k5, dim3(128), dim3(256), 0, stream, hend, decay, H0);
    hipLaunchKernelGGL(k6, dim3(1024), dim3(128), 0, stream, convT, dtT, gate, Antab, An2tab, Dp, H0, x, outp);
}

// Round 2
// 143.462 us; speedup vs baseline: 1.1352x; 1.1352x over previous
//
#include <hip/hip_runtime.h>
#include <hip/hip_bf16.h>
#include <stdint.h>

#define BB 16
#define CC 128
#define HH 64
#define WW 64
#define LL 4096
#define SS 16
#define NCH 64
#define CT 64

typedef __attribute__((ext_vector_type(4))) float f32x4;
typedef __attribute__((ext_vector_type(8))) short short8;
typedef __attribute__((ext_vector_type(4))) unsigned int u32x4;

#define AS1 __attribute__((address_space(1)))
#define AS3 __attribute__((address_space(3)))

__device__ __forceinline__ float bf2f(unsigned short u) {
    union { unsigned int i; float f; } v;
    v.i = ((unsigned int)u) << 16;
    return v.f;
}
__device__ __forceinline__ unsigned short f2bf(float f) {
    union { float f; unsigned int i; } v;
    v.f = f;
    unsigned int x = v.i;
    return (unsigned short)((x + 0x7fffu + ((x >> 16) & 1u)) >> 16);
}
__device__ __forceinline__ float fexp2(float x) { return __builtin_amdgcn_exp2f(x); }

// ---------------- K0a: weight fragment transforms + An/Dp tables ----------------
__global__ void k0a(const float* __restrict__ conv_w, const float* __restrict__ dt_w,
                    const float* __restrict__ A, const float* __restrict__ Dv,
                    short* __restrict__ wf, short* __restrict__ wdtf,
                    float* __restrict__ An, float* __restrict__ An2, float* __restrict__ Dp) {
    int idx = blockIdx.x * 256 + threadIdx.x;
    if (idx < 18432) {
        // conv weight frags: frag fr = ((tp*4+ks)*8+nfg), value B[k=cin][n=cout]
        int lane = idx & 63, fr = idx >> 6;
        int nfg = fr & 7, ks = (fr >> 3) & 3, tp = fr >> 5;
        int dy = tp / 3, dx = tp % 3;
        int cout = nfg * 16 + (lane & 15);
        int cin0 = ks * 32 + (lane >> 4) * 8;
        short8 v;
#pragma unroll
        for (int j = 0; j < 8; ++j)
            v[j] = (short)f2bf(conv_w[((cout * CC + cin0 + j) * 3 + dy) * 3 + dx]);
        *(short8*)(wf + (size_t)idx * 8) = v;
    } else if (idx < 20480) {
        int i2 = idx - 18432;
        int lane = i2 & 63, fr = i2 >> 6;
        int nfg = fr & 7, ks = fr >> 3;
        int o = nfg * 16 + (lane & 15);
        int c0 = ks * 32 + (lane >> 4) * 8;
        short8 v;
#pragma unroll
        for (int j = 0; j < 8; ++j) v[j] = (short)f2bf(dt_w[o * CC + c0 + j]);
        *(short8*)(wdtf + (size_t)i2 * 8) = v;
    } else if (idx < 22528) {
        int i3 = idx - 20480;
        float a = -expf(A[i3]);
        An[i3] = a;
        An2[i3] = a * 1.4426950408889634f;
    } else if (idx < 22656) {
        int c = idx - 22528;
        Dp[c] = expf(Dv[c]);
    }
}

// ---------------- K0b: transpose x[b][c][t] -> xT[b][t][c] (bf16) ----------------
__global__ __launch_bounds__(256) void k0b(const float* __restrict__ x, unsigned short* __restrict__ xT) {
    __shared__ float lt[64][65];
    int bid = blockIdx.x;             // 2048
    int b = bid >> 7, rem = bid & 127;
    int tt = rem >> 1, ct = rem & 1;
    int t0 = tt * 64, c0 = ct * 64;
    int tid = threadIdx.x;
    int colr = tid & 63, rowb = tid >> 6;  // rowb 0..3
#pragma unroll
    for (int r = 0; r < 16; ++r) {
        int row = rowb + r * 4;  // c-local
        lt[row][colr] = x[(size_t)(b * CC + c0 + row) * LL + t0 + colr];
    }
    __syncthreads();
#pragma unroll
    for (int r = 0; r < 16; ++r) {
        int trow = rowb + r * 4;  // t-local
        xT[((size_t)b * LL + t0 + trow) * CC + c0 + colr] = f2bf(lt[colr][trow]);
    }
}

// ---------------- K1: 3x3 conv via MFMA implicit GEMM ----------------
__global__ __launch_bounds__(256) void k1(const unsigned short* __restrict__ xT,
                                          const short* __restrict__ wf,
                                          const float* __restrict__ conv_b,
                                          unsigned short* __restrict__ convT,
                                          float* __restrict__ pooled) {
    __shared__ __align__(16) unsigned short slab[3 * 66 * 128];  // 50688 B
    int bid = blockIdx.x;
    int b = bid >> 6, h = bid & 63;
    int tid = threadIdx.x;
    int wave = tid >> 6, lane = tid & 63;

    // zero halo rows (tok 0 and tok 65 of each dy): 3*2*256B
    if (tid < 96) {
        int dy = tid >> 5, r = (tid >> 4) & 1, j = tid & 15;
        u32x4 z = {0, 0, 0, 0};
        *(u32x4*)((char*)slab + dy * 16896 + (r ? 16640 : 0) + j * 16) = z;
    }
#pragma unroll
    for (int dy = 0; dy < 3; ++dy) {
        int hs = h + dy - 1;
        char* slabdy = (char*)slab + dy * 16896;
        if (hs >= 0 && hs < HH) {
            const char* src = (const char*)xT + (size_t)(b * LL + hs * 64) * 256;
#pragma unroll
            for (int i = 0; i < 4; ++i) {
                unsigned int Xbase = 256u + (unsigned)i * 4096u + (unsigned)wave * 1024u;
                unsigned int X = Xbase + (unsigned)lane * 16u;
                unsigned int tok = X >> 8;
                unsigned int srcoff = ((X & ~255u) - 256u) | ((X & 255u) ^ ((tok & 7u) << 4));
                __builtin_amdgcn_global_load_lds((const AS1 unsigned int*)(src + srcoff),
                                                 (AS3 unsigned int*)(slabdy + Xbase), 16, 0, 0);
            }
        } else {
            u32x4 z = {0, 0, 0, 0};
#pragma unroll
            for (int i = 0; i < 4; ++i)
                *(u32x4*)(slabdy + 256 + tid * 64 + i * 16) = z;
        }
    }
    __syncthreads();

    int lm = lane & 15, lg = lane >> 4;
    f32x4 acc[4][2];
#pragma unroll
    for (int m = 0; m < 4; ++m)
#pragma unroll
        for (int n = 0; n < 2; ++n) acc[m][n] = (f32x4){0.f, 0.f, 0.f, 0.f};

#pragma unroll
    for (int tp = 0; tp < 9; ++tp) {
        int dy = tp / 3, dx = tp % 3;
        const char* slabdy = (const char*)slab + dy * 16896;
#pragma unroll
        for (int ks = 0; ks < 4; ++ks) {
            short8 bf0 = *(const short8*)(wf + ((size_t)(((tp * 4 + ks) * 8) + wave * 2 + 0) * 64 + lane) * 8);
            short8 bf1 = *(const short8*)(wf + ((size_t)(((tp * 4 + ks) * 8) + wave * 2 + 1) * 64 + lane) * 8);
#pragma unroll
            for (int mf = 0; mf < 4; ++mf) {
                int tok = mf * 16 + lm + dx;
                unsigned int off = (unsigned)((tok * 256 + ks * 64 + lg * 16) ^ ((tok & 7) << 4));
                short8 af = *(const short8*)(slabdy + off);
                acc[mf][0] = __builtin_amdgcn_mfma_f32_16x16x32_bf16(af, bf0, acc[mf][0], 0, 0, 0);
                acc[mf][1] = __builtin_amdgcn_mfma_f32_16x16x32_bf16(af, bf1, acc[mf][1], 0, 0, 0);
            }
        }
    }

    // epilogue: bias, write convT bf16, pooling partials
    int n0w = wave * 32;
    size_t tokbase = (size_t)(b * LL + h * 64);
    float psum[2] = {0.f, 0.f};
#pragma unroll
    for (int nf = 0; nf < 2; ++nf) {
        int n = n0w + nf * 16 + lm;
        float bias = conv_b[n];
#pragma unroll
        for (int mf = 0; mf < 4; ++mf)
#pragma unroll
            for (int r = 0; r < 4; ++r) {
                int w = mf * 16 + lg * 4 + r;
                float v = acc[mf][nf][r] + bias;
                convT[(tokbase + w) * CC + n] = f2bf(v);
                psum[nf] += v;
            }
    }
#pragma unroll
    for (int nf = 0; nf < 2; ++nf) {
        float s = psum[nf];
        s += __shfl_xor(s, 16);
        s += __shfl_xor(s, 32);
        if (lane < 16) atomicAdd(&pooled[b * CC + n0w + nf * 16 + lane], s);
    }
}

// ---------------- K2: spectral gate ----------------
__global__ __launch_bounds__(128) void k2(const float* __restrict__ pooled, const float* __restrict__ g1w,
                                          const float* __restrict__ g1b, const float* __restrict__ g2w,
                                          const float* __restrict__ g2b, float* __restrict__ gate) {
    __shared__ float wl[128 * 129];
    __shared__ float meanr[128];
    __shared__ float garr[128];
    int b = blockIdx.x;
    int tid = threadIdx.x;  // 128
    meanr[tid] = pooled[b * CC + tid] * (1.f / 4096.f);
#pragma unroll 4
    for (int i = 0; i < 128; ++i) wl[i * 129 + tid] = g1w[i * 128 + tid];
    __syncthreads();
    float acc = g1b[tid];
    for (int c = 0; c < 128; ++c) acc += meanr[c] * wl[tid * 129 + c];
    garr[tid] = fmaxf(acc, 0.f);
    __syncthreads();
#pragma unroll 4
    for (int i = 0; i < 128; ++i) wl[i * 129 + tid] = g2w[i * 128 + tid];
    __syncthreads();
    float acc2 = g2b[tid];
    for (int c = 0; c < 128; ++c) acc2 += garr[c] * wl[tid * 129 + c];
    gate[b * CC + tid] = __builtin_amdgcn_rcpf(1.f + fexp2(-1.4426950408889634f * acc2));
}

// ---------------- K3: dt = sigmoid((convT*gate) @ dt_w^T + dt_b) ----------------
__global__ __launch_bounds__(256) void k3(const unsigned short* __restrict__ convT,
                                          const short* __restrict__ wdtf,
                                          const float* __restrict__ gate,
                                          const float* __restrict__ dt_b,
                                          unsigned short* __restrict__ dtT) {
    __shared__ __align__(16) unsigned short albuf[128 * 128];  // 32KB
    __shared__ float gl[128];
    int bid = blockIdx.x;
    int b = bid >> 5, t0 = (bid & 31) * 128;
    int tid = threadIdx.x;
    int wave = tid >> 6, lane = tid & 63;
    if (tid < 128) gl[tid] = gate[b * CC + tid];
    __syncthreads();
    const char* srcb = (const char*)convT + (size_t)(b * LL + t0) * 256;
#pragma unroll
    for (int i = 0; i < 8; ++i) {
        unsigned int byteoff = (unsigned)((i * 256 + tid) * 16);
        unsigned int tok = byteoff >> 8;
        unsigned int inner = byteoff & 255u;
        int c8 = (int)(inner >> 1);
        short8 v = *(const short8*)(srcb + (size_t)tok * 256 + inner);
#pragma unroll
        for (int j = 0; j < 8; ++j) {
            float f = bf2f((unsigned short)v[j]) * gl[c8 + j];
            v[j] = (short)f2bf(f);
        }
        *(short8*)((char*)albuf + (byteoff ^ ((tok & 7u) << 4))) = v;
    }
    __syncthreads();

    int lm = lane & 15, lg = lane >> 4;
    f32x4 acc[8][2];
#pragma unroll
    for (int m = 0; m < 8; ++m)
#pragma unroll
        for (int n = 0; n < 2; ++n) acc[m][n] = (f32x4){0.f, 0.f, 0.f, 0.f};
#pragma unroll
    for (int ks = 0; ks < 4; ++ks) {
        short8 bf0 = *(const short8*)(wdtf + ((size_t)((ks * 8) + wave * 2 + 0) * 64 + lane) * 8);
        short8 bf1 = *(const short8*)(wdtf + ((size_t)((ks * 8) + wave * 2 + 1) * 64 + lane) * 8);
#pragma unroll
        for (int mf = 0; mf < 8; ++mf) {
            int tok = mf * 16 + lm;
            unsigned int off = (unsigned)((tok * 256 + ks * 64 + lg * 16) ^ ((tok & 7) << 4));
            short8 af = *(const short8*)((const char*)albuf + off);
            acc[mf][0] = __builtin_amdgcn_mfma_f32_16x16x32_bf16(af, bf0, acc[mf][0], 0, 0, 0);
            acc[mf][1] = __builtin_amdgcn_mfma_f32_16x16x32_bf16(af, bf1, acc[mf][1], 0, 0, 0);
        }
    }
#pragma unroll
    for (int nf = 0; nf < 2; ++nf) {
        int o = wave * 32 + nf * 16 + lm;
        float zb = dt_b[o];
#pragma unroll
        for (int mf = 0; mf < 8; ++mf)
#pragma unroll
            for (int r = 0; r < 4; ++r) {
                int tok = mf * 16 + lg * 4 + r;
                float z = acc[mf][nf][r] + zb;
                float d = __builtin_amdgcn_rcpf(1.f + fexp2(-1.4426950408889634f * z));
                dtT[(size_t)(b * LL + t0 + tok) * CC + o] = f2bf(d);
            }
    }
}

// ---------------- K4: scan phase 1 (local chunk states + decay) ----------------
__global__ __launch_bounds__(128) void k4(const unsigned short* __restrict__ convT,
                                          const unsigned short* __restrict__ dtT,
                                          const float* __restrict__ gate,
                                          const float* __restrict__ An2,
                                          float* __restrict__ hend, float* __restrict__ decay) {
    int bid = blockIdx.x;
    int b = bid >> 6, ch = bid & 63;
    int c = threadIdx.x;
    float a2[SS], h[SS];
#pragma unroll
    for (int s = 0; s < SS; ++s) {
        a2[s] = An2[c * SS + s];
        h[s] = 0.f;
    }
    float g = gate[b * CC + c];
    float sdt = 0.f;
    int t0 = ch * CT;
    const unsigned short* xp = convT + (size_t)(b * LL + t0) * CC + c;
    const unsigned short* dp = dtT + (size_t)(b * LL + t0) * CC + c;
#pragma unroll 4
    for (int t = 0; t < CT; ++t) {
        float x = bf2f(xp[t * CC]) * g;
        float d = bf2f(dp[t * CC]);
        sdt += d;
#pragma unroll
        for (int s = 0; s < SS; ++s) h[s] = h[s] * fexp2(a2[s] * d) + x;
    }
    size_t base = ((size_t)(b * NCH + ch) * CC + c) * SS;
#pragma unroll
    for (int s = 0; s < SS; ++s) {
        hend[base + s] = h[s];
        decay[base + s] = fexp2(a2[s] * sdt);
    }
}

// ---------------- K5: sequential chunk combine ----------------
__global__ __launch_bounds__(256) void k5(const float* __restrict__ hend, const float* __restrict__ decay,
                                          float* __restrict__ H0) {
    int idx = blockIdx.x * 256 + threadIdx.x;  // 32768
    int b = idx >> 11, rem = idx & 2047;
    float Hv = 0.f;
    for (int k = 0; k < NCH; ++k) {
        size_t base = (size_t)(b * NCH + k) * 2048 + rem;
        H0[base] = Hv;
        Hv = hend[base] + Hv * decay[base];
    }
}

// ---------------- K6: scan phase 2 (emit y + identity, coalesced via LDS) ----------------
__global__ __launch_bounds__(128) void k6(const unsigned short* __restrict__ convT,
                                          const unsigned short* __restrict__ dtT,
                                          const float* __restrict__ gate,
                                          const float* __restrict__ Antab,
                                          const float* __restrict__ An2tab,
                                          const float* __restrict__ Dp,
                                          const float* __restrict__ H0,
                                          const float* __restrict__ xin,
                                          float* __restrict__ out) {
    __shared__ float ylds[128][65];
    int bid = blockIdx.x;
    int b = bid >> 6, ch = bid & 63;
    int c = threadIdx.x;
    float a2[SS], an[SS], h[SS];
#pragma unroll
    for (int s = 0; s < SS; ++s) {
        a2[s] = An2tab[c * SS + s];
        an[s] = Antab[c * SS + s];
    }
    size_t hbase = ((size_t)(b * NCH + ch) * CC + c) * SS;
#pragma unroll
    for (int s = 0; s < SS; ++s) h[s] = H0[hbase + s];
    float g = gate[b * CC + c];
    float dpc = Dp[c];
    int t0 = ch * CT;
    const unsigned short* xp = convT + (size_t)(b * LL + t0) * CC + c;
    const unsigned short* dp = dtT + (size_t)(b * LL + t0) * CC + c;
#pragma unroll 4
    for (int t = 0; t < CT; ++t) {
        float x = bf2f(xp[t * CC]) * g;
        float d = bf2f(dp[t * CC]);
        float y = dpc * x;
#pragma unroll
        for (int s = 0; s < SS; ++s) {
            h[s] = h[s] * fexp2(a2[s] * d) + x;
            y += h[s] * an[s];
        }
        ylds[c][t] = y;
    }
    __syncthreads();
    // coalesced output: each wave writes one (b,row) segment of 64 contiguous floats
    int tt = c & 63, rh = c >> 6;
    size_t outbase = (size_t)b * CC * LL + t0 + tt;
#pragma unroll 4
    for (int rr = 0; rr < 64; ++rr) {
        int row = rr * 2 + rh;
        size_t gi = outbase + (size_t)row * LL;
        out[gi] = ylds[row][tt] + xin[gi];
    }
}

extern "C" void kernel_launch(void* const* d_in, const int* in_sizes, int n_in,
                              void* d_out, int out_size, void* d_ws, size_t ws_size,
                              hipStream_t stream) {
    const float* x      = (const float*)d_in[0];
    const float* conv_w = (const float*)d_in[1];
    const float* conv_b = (const float*)d_in[2];
    const float* dt_w   = (const float*)d_in[3];
    const float* dt_b   = (const float*)d_in[4];
    const float* A      = (const float*)d_in[5];
    const float* D      = (const float*)d_in[6];
    const float* g1w    = (const float*)d_in[7];
    const float* g1b    = (const float*)d_in[8];
    const float* g2w    = (const float*)d_in[9];
    const float* g2b    = (const float*)d_in[10];

    char* ws = (char*)d_ws;
    // layout (xT overlaid by hend/decay after K1's last read of xT)
    unsigned short* xT    = (unsigned short*)(ws + 0);          // 16.78 MB
    float* hend           = (float*)(ws + 0);                   //  8.39 MB (after K1)
    float* decay          = (float*)(ws + 8388608);             //  8.39 MB
    unsigned short* convT = (unsigned short*)(ws + 16777216);   // 16.78 MB
    unsigned short* dtT   = (unsigned short*)(ws + 33554432);   // 16.78 MB
    float* H0             = (float*)(ws + 50331648);            //  8.39 MB
    short* wf             = (short*)(ws + 58720256);            //  294912 B
    short* wdtf           = (short*)(ws + 59015168);            //  32768 B
    float* pooled         = (float*)(ws + 59047936);            //  8192 B
    float* gate           = (float*)(ws + 59056128);            //  8192 B
    float* Antab          = (float*)(ws + 59064320);            //  8192 B
    float* An2tab         = (float*)(ws + 59072512);            //  8192 B
    float* Dp             = (float*)(ws + 59080704);            //  512 B
    float* outp           = (float*)d_out;

    hipMemsetAsync(pooled, 0, BB * CC * sizeof(float), stream);
    hipLaunchKernelGGL(k0a, dim3(89), dim3(256), 0, stream, conv_w, dt_w, A, D, wf, wdtf, Antab, An2tab, Dp);
    hipLaunchKernelGGL(k0b, dim3(2048), dim3(256), 0, stream, x, xT);
    hipLaunchKernelGGL(k1, dim3(1024), dim3(256), 0, stream, xT, wf, conv_b, convT, pooled);
    hipLaunchKernelGGL(k2, dim3(16), dim3(128), 0, stream, pooled, g1w, g1b, g2w, g2b, gate);
    hipLaunchKernelGGL(k3, dim3(512), dim3(256), 0, stream, convT, wdtf, gate, dt_b, dtT);
    hipLaunchKernelGGL(k4, dim3(1024), dim3(128), 0, stream, convT, dtT, gate, An2tab, hend, decay);
    hipLaunchKernelGGL(k5, dim3(128), dim3(256), 0, stream, hend, decay, H0);
    hipLaunchKernelGGL(k6, dim3(1024), dim3(128), 0, stream, convT, dtT, gate, Antab, An2tab, Dp, H0, x, outp);
}

// Round 3
// 135.077 us; speedup vs baseline: 1.2056x; 1.0621x over previous
//
#include <hip/hip_runtime.h>
#include <hip/hip_bf16.h>
#include <stdint.h>

#define BB 16
#define CC 128
#define HH 64
#define WW 64
#define LL 4096
#define SS 16
#define NCH 64
#define CT 64

typedef __attribute__((ext_vector_type(4))) float f32x4;
typedef __attribute__((ext_vector_type(8))) short short8;
typedef __attribute__((ext_vector_type(4))) unsigned int u32x4;

#define AS1 __attribute__((address_space(1)))
#define AS3 __attribute__((address_space(3)))

__device__ __forceinline__ float bf2f(unsigned short u) {
    union { unsigned int i; float f; } v;
    v.i = ((unsigned int)u) << 16;
    return v.f;
}
__device__ __forceinline__ unsigned short f2bf(float f) {
    union { float f; unsigned int i; } v;
    v.f = f;
    unsigned int x = v.i;
    return (unsigned short)((x + 0x7fffu + ((x >> 16) & 1u)) >> 16);
}
__device__ __forceinline__ float fexp2(float x) { return __builtin_amdgcn_exp2f(x); }

// ---------------- K0a: weight fragment transforms + An/Dp tables + pooled zero ----------------
__global__ void k0a(const float* __restrict__ conv_w, const float* __restrict__ dt_w,
                    const float* __restrict__ A, const float* __restrict__ Dv,
                    short* __restrict__ wf, short* __restrict__ wdtf,
                    float* __restrict__ An, float* __restrict__ An2, float* __restrict__ Dp,
                    float* __restrict__ pooled) {
    int idx = blockIdx.x * 256 + threadIdx.x;
    if (idx < 18432) {
        // conv weight frags: frag fr = ((tp*4+ks)*8+nfg), value B[k=cin][n=cout]
        int lane = idx & 63, fr = idx >> 6;
        int nfg = fr & 7, ks = (fr >> 3) & 3, tp = fr >> 5;
        int dy = tp / 3, dx = tp % 3;
        int cout = nfg * 16 + (lane & 15);
        int cin0 = ks * 32 + (lane >> 4) * 8;
        short8 v;
#pragma unroll
        for (int j = 0; j < 8; ++j)
            v[j] = (short)f2bf(conv_w[((cout * CC + cin0 + j) * 3 + dy) * 3 + dx]);
        *(short8*)(wf + (size_t)idx * 8) = v;
    } else if (idx < 20480) {
        int i2 = idx - 18432;
        int lane = i2 & 63, fr = i2 >> 6;
        int nfg = fr & 7, ks = fr >> 3;
        int o = nfg * 16 + (lane & 15);
        int c0 = ks * 32 + (lane >> 4) * 8;
        short8 v;
#pragma unroll
        for (int j = 0; j < 8; ++j) v[j] = (short)f2bf(dt_w[o * CC + c0 + j]);
        *(short8*)(wdtf + (size_t)i2 * 8) = v;
    } else if (idx < 22528) {
        int i3 = idx - 20480;
        float a = -expf(A[i3]);
        An[i3] = a;
        An2[i3] = a * 1.4426950408889634f;
    } else if (idx < 22656) {
        int c = idx - 22528;
        Dp[c] = expf(Dv[c]);
    } else if (idx < 24704) {
        pooled[idx - 22656] = 0.f;
    }
}

// ---------------- K0b: transpose x[b][c][t] -> xT[b][t][c] (bf16) ----------------
__global__ __launch_bounds__(256) void k0b(const float* __restrict__ x, unsigned short* __restrict__ xT) {
    __shared__ float lt[64][65];
    int bid = blockIdx.x;             // 2048
    int b = bid >> 7, rem = bid & 127;
    int tt = rem >> 1, ct = rem & 1;
    int t0 = tt * 64, c0 = ct * 64;
    int tid = threadIdx.x;
    int colr = tid & 63, rowb = tid >> 6;  // rowb 0..3
#pragma unroll
    for (int r = 0; r < 16; ++r) {
        int row = rowb + r * 4;  // c-local
        lt[row][colr] = x[(size_t)(b * CC + c0 + row) * LL + t0 + colr];
    }
    __syncthreads();
#pragma unroll
    for (int r = 0; r < 16; ++r) {
        int trow = rowb + r * 4;  // t-local
        xT[((size_t)b * LL + t0 + trow) * CC + c0 + colr] = f2bf(lt[colr][trow]);
    }
}

// ---------------- K1: 3x3 conv via MFMA implicit GEMM ----------------
__global__ __launch_bounds__(256) void k1(const unsigned short* __restrict__ xT,
                                          const short* __restrict__ wf,
                                          const float* __restrict__ conv_b,
                                          unsigned short* __restrict__ convT,
                                          float* __restrict__ pooled) {
    __shared__ __align__(16) unsigned short slab[3 * 66 * 128];  // 50688 B
    int bid = blockIdx.x;
    int b = bid >> 6, h = bid & 63;
    int tid = threadIdx.x;
    int wave = tid >> 6, lane = tid & 63;

    // zero halo rows (tok 0 and tok 65 of each dy): 3*2*256B
    if (tid < 96) {
        int dy = tid >> 5, r = (tid >> 4) & 1, j = tid & 15;
        u32x4 z = {0, 0, 0, 0};
        *(u32x4*)((char*)slab + dy * 16896 + (r ? 16640 : 0) + j * 16) = z;
    }
#pragma unroll
    for (int dy = 0; dy < 3; ++dy) {
        int hs = h + dy - 1;
        char* slabdy = (char*)slab + dy * 16896;
        if (hs >= 0 && hs < HH) {
            const char* src = (const char*)xT + (size_t)(b * LL + hs * 64) * 256;
#pragma unroll
            for (int i = 0; i < 4; ++i) {
                unsigned int Xbase = 256u + (unsigned)i * 4096u + (unsigned)wave * 1024u;
                unsigned int X = Xbase + (unsigned)lane * 16u;
                unsigned int tok = X >> 8;
                unsigned int srcoff = ((X & ~255u) - 256u) | ((X & 255u) ^ ((tok & 7u) << 4));
                __builtin_amdgcn_global_load_lds((const AS1 unsigned int*)(src + srcoff),
                                                 (AS3 unsigned int*)(slabdy + Xbase), 16, 0, 0);
            }
        } else {
            u32x4 z = {0, 0, 0, 0};
#pragma unroll
            for (int i = 0; i < 4; ++i)
                *(u32x4*)(slabdy + 256 + tid * 64 + i * 16) = z;
        }
    }
    __syncthreads();

    int lm = lane & 15, lg = lane >> 4;
    f32x4 acc[4][2];
#pragma unroll
    for (int m = 0; m < 4; ++m)
#pragma unroll
        for (int n = 0; n < 2; ++n) acc[m][n] = (f32x4){0.f, 0.f, 0.f, 0.f};

#pragma unroll
    for (int tp = 0; tp < 9; ++tp) {
        int dy = tp / 3, dx = tp % 3;
        const char* slabdy = (const char*)slab + dy * 16896;
#pragma unroll
        for (int ks = 0; ks < 4; ++ks) {
            short8 bf0 = *(const short8*)(wf + ((size_t)(((tp * 4 + ks) * 8) + wave * 2 + 0) * 64 + lane) * 8);
            short8 bf1 = *(const short8*)(wf + ((size_t)(((tp * 4 + ks) * 8) + wave * 2 + 1) * 64 + lane) * 8);
#pragma unroll
            for (int mf = 0; mf < 4; ++mf) {
                int tok = mf * 16 + lm + dx;
                unsigned int off = (unsigned)((tok * 256 + ks * 64 + lg * 16) ^ ((tok & 7) << 4));
                short8 af = *(const short8*)(slabdy + off);
                acc[mf][0] = __builtin_amdgcn_mfma_f32_16x16x32_bf16(af, bf0, acc[mf][0], 0, 0, 0);
                acc[mf][1] = __builtin_amdgcn_mfma_f32_16x16x32_bf16(af, bf1, acc[mf][1], 0, 0, 0);
            }
        }
    }

    // epilogue: bias, write convT bf16, pooling partials
    int n0w = wave * 32;
    size_t tokbase = (size_t)(b * LL + h * 64);
    float psum[2] = {0.f, 0.f};
#pragma unroll
    for (int nf = 0; nf < 2; ++nf) {
        int n = n0w + nf * 16 + lm;
        float bias = conv_b[n];
#pragma unroll
        for (int mf = 0; mf < 4; ++mf)
#pragma unroll
            for (int r = 0; r < 4; ++r) {
                int w = mf * 16 + lg * 4 + r;
                float v = acc[mf][nf][r] + bias;
                convT[(tokbase + w) * CC + n] = f2bf(v);
                psum[nf] += v;
            }
    }
#pragma unroll
    for (int nf = 0; nf < 2; ++nf) {
        float s = psum[nf];
        s += __shfl_xor(s, 16);
        s += __shfl_xor(s, 32);
        if (lane < 16) atomicAdd(&pooled[b * CC + n0w + nf * 16 + lane], s);
    }
}

// ---------------- K2: spectral gate ----------------
__global__ __launch_bounds__(128) void k2(const float* __restrict__ pooled, const float* __restrict__ g1w,
                                          const float* __restrict__ g1b, const float* __restrict__ g2w,
                                          const float* __restrict__ g2b, float* __restrict__ gate) {
    __shared__ float wl[128 * 129];
    __shared__ float meanr[128];
    __shared__ float garr[128];
    int b = blockIdx.x;
    int tid = threadIdx.x;  // 128
    meanr[tid] = pooled[b * CC + tid] * (1.f / 4096.f);
#pragma unroll 4
    for (int i = 0; i < 128; ++i) wl[i * 129 + tid] = g1w[i * 128 + tid];
    __syncthreads();
    float acc = g1b[tid];
    for (int c = 0; c < 128; ++c) acc += meanr[c] * wl[tid * 129 + c];
    garr[tid] = fmaxf(acc, 0.f);
    __syncthreads();
#pragma unroll 4
    for (int i = 0; i < 128; ++i) wl[i * 129 + tid] = g2w[i * 128 + tid];
    __syncthreads();
    float acc2 = g2b[tid];
    for (int c = 0; c < 128; ++c) acc2 += garr[c] * wl[tid * 129 + c];
    gate[b * CC + tid] = __builtin_amdgcn_rcpf(1.f + fexp2(-1.4426950408889634f * acc2));
}

// ---------------- K3: dt GEMM + sigmoid + fused scan phase-1 ----------------
__global__ __launch_bounds__(256) void k3(const unsigned short* __restrict__ convT,
                                          const short* __restrict__ wdtf,
                                          const float* __restrict__ gate,
                                          const float* __restrict__ dt_b,
                                          const float* __restrict__ An2,
                                          unsigned short* __restrict__ dtT,
                                          float* __restrict__ hend, float* __restrict__ decay) {
    __shared__ __align__(16) unsigned short albuf[128 * 128];   // 32KB gated-x (swizzled)
    __shared__ __align__(16) unsigned short dtl[128 * 136];     // 34KB dt (stride-136)
    __shared__ float gl[128];
    int bid = blockIdx.x;
    int b = bid >> 5, tile = bid & 31, t0 = tile * 128;
    int tid = threadIdx.x;
    int wave = tid >> 6, lane = tid & 63;
    if (tid < 128) gl[tid] = gate[b * CC + tid];
    __syncthreads();
    const char* srcb = (const char*)convT + (size_t)(b * LL + t0) * 256;
#pragma unroll
    for (int i = 0; i < 8; ++i) {
        unsigned int byteoff = (unsigned)((i * 256 + tid) * 16);
        unsigned int tok = byteoff >> 8;
        unsigned int inner = byteoff & 255u;
        int c8 = (int)(inner >> 1);
        short8 v = *(const short8*)(srcb + (size_t)tok * 256 + inner);
#pragma unroll
        for (int j = 0; j < 8; ++j) {
            float f = bf2f((unsigned short)v[j]) * gl[c8 + j];
            v[j] = (short)f2bf(f);
        }
        *(short8*)((char*)albuf + (byteoff ^ ((tok & 7u) << 4))) = v;
    }
    __syncthreads();

    int lm = lane & 15, lg = lane >> 4;
    f32x4 acc[8][2];
#pragma unroll
    for (int m = 0; m < 8; ++m)
#pragma unroll
        for (int n = 0; n < 2; ++n) acc[m][n] = (f32x4){0.f, 0.f, 0.f, 0.f};
#pragma unroll
    for (int ks = 0; ks < 4; ++ks) {
        short8 bf0 = *(const short8*)(wdtf + ((size_t)((ks * 8) + wave * 2 + 0) * 64 + lane) * 8);
        short8 bf1 = *(const short8*)(wdtf + ((size_t)((ks * 8) + wave * 2 + 1) * 64 + lane) * 8);
#pragma unroll
        for (int mf = 0; mf < 8; ++mf) {
            int tok = mf * 16 + lm;
            unsigned int off = (unsigned)((tok * 256 + ks * 64 + lg * 16) ^ ((tok & 7) << 4));
            short8 af = *(const short8*)((const char*)albuf + off);
            acc[mf][0] = __builtin_amdgcn_mfma_f32_16x16x32_bf16(af, bf0, acc[mf][0], 0, 0, 0);
            acc[mf][1] = __builtin_amdgcn_mfma_f32_16x16x32_bf16(af, bf1, acc[mf][1], 0, 0, 0);
        }
    }
#pragma unroll
    for (int nf = 0; nf < 2; ++nf) {
        int o = wave * 32 + nf * 16 + lm;
        float zb = dt_b[o];
#pragma unroll
        for (int mf = 0; mf < 8; ++mf)
#pragma unroll
            for (int r = 0; r < 4; ++r) {
                int tok = mf * 16 + lg * 4 + r;
                float z = acc[mf][nf][r] + zb;
                float d = __builtin_amdgcn_rcpf(1.f + fexp2(-1.4426950408889634f * z));
                unsigned short ub = f2bf(d);
                dtT[(size_t)(b * LL + t0 + tok) * CC + o] = ub;
                dtl[tok * 136 + o] = ub;
            }
    }
    __syncthreads();

    // fused scan phase-1: 2 chunks x 128 channels; x from albuf (gated), dt from dtl
    int half = tid >> 7, c = tid & 127;
    int ch = tile * 2 + half;
    float a2[SS], h[SS];
#pragma unroll
    for (int s = 0; s < SS; ++s) {
        a2[s] = An2[c * SS + s];
        h[s] = 0.f;
    }
    float sdt = 0.f;
#pragma unroll 4
    for (int t = 0; t < CT; ++t) {
        int tokb = half * 64 + t;
        unsigned int xoff = ((unsigned)(tokb * 256 + c * 2)) ^ (((unsigned)tokb & 7u) << 4);
        float x = bf2f(*(const unsigned short*)((const char*)albuf + xoff));
        float d = bf2f(dtl[tokb * 136 + c]);
        sdt += d;
#pragma unroll
        for (int s = 0; s < SS; ++s) h[s] = h[s] * fexp2(a2[s] * d) + x;
    }
    size_t base = ((size_t)(b * NCH + ch) * CC + c) * SS;
#pragma unroll
    for (int q = 0; q < 4; ++q) {
        f32x4 hv, dv;
#pragma unroll
        for (int j = 0; j < 4; ++j) {
            hv[j] = h[q * 4 + j];
            dv[j] = fexp2(a2[q * 4 + j] * sdt);
        }
        *(f32x4*)(hend + base + q * 4) = hv;
        *(f32x4*)(decay + base + q * 4) = dv;
    }
}

// ---------------- K5: sequential chunk combine ----------------
__global__ __launch_bounds__(256) void k5(const float* __restrict__ hend, const float* __restrict__ decay,
                                          float* __restrict__ H0) {
    int idx = blockIdx.x * 256 + threadIdx.x;  // 32768
    int b = idx >> 11, rem = idx & 2047;
    float Hv = 0.f;
    for (int k = 0; k < NCH; ++k) {
        size_t base = (size_t)(b * NCH + k) * 2048 + rem;
        H0[base] = Hv;
        Hv = hend[base] + Hv * decay[base];
    }
}

// ---------------- K6: scan phase 2 (emit y + identity, coalesced via LDS) ----------------
__global__ __launch_bounds__(128) void k6(const unsigned short* __restrict__ convT,
                                          const unsigned short* __restrict__ dtT,
                                          const float* __restrict__ gate,
                                          const float* __restrict__ Antab,
                                          const float* __restrict__ An2tab,
                                          const float* __restrict__ Dp,
                                          const float* __restrict__ H0,
                                          const float* __restrict__ xin,
                                          float* __restrict__ out) {
    __shared__ float ylds[128][65];
    int bid = blockIdx.x;
    int b = bid >> 6, ch = bid & 63;
    int c = threadIdx.x;
    float a2[SS], an[SS], h[SS];
#pragma unroll
    for (int s = 0; s < SS; ++s) {
        a2[s] = An2tab[c * SS + s];
        an[s] = Antab[c * SS + s];
    }
    size_t hbase = ((size_t)(b * NCH + ch) * CC + c) * SS;
#pragma unroll
    for (int s = 0; s < SS; ++s) h[s] = H0[hbase + s];
    float g = gate[b * CC + c];
    float dpc = Dp[c];
    int t0 = ch * CT;
    const unsigned short* xp = convT + (size_t)(b * LL + t0) * CC + c;
    const unsigned short* dp = dtT + (size_t)(b * LL + t0) * CC + c;
#pragma unroll 4
    for (int t = 0; t < CT; ++t) {
        float x = bf2f(xp[t * CC]) * g;
        float d = bf2f(dp[t * CC]);
        float y = dpc * x;
#pragma unroll
        for (int s = 0; s < SS; ++s) {
            h[s] = h[s] * fexp2(a2[s] * d) + x;
            y += h[s] * an[s];
        }
        ylds[c][t] = y;
    }
    __syncthreads();
    // coalesced output: each wave writes one (b,row) segment of 64 contiguous floats
    int tt = c & 63, rh = c >> 6;
    size_t outbase = (size_t)b * CC * LL + t0 + tt;
#pragma unroll 4
    for (int rr = 0; rr < 64; ++rr) {
        int row = rr * 2 + rh;
        size_t gi = outbase + (size_t)row * LL;
        out[gi] = ylds[row][tt] + xin[gi];
    }
}

extern "C" void kernel_launch(void* const* d_in, const int* in_sizes, int n_in,
                              void* d_out, int out_size, void* d_ws, size_t ws_size,
                              hipStream_t stream) {
    const float* x      = (const float*)d_in[0];
    const float* conv_w = (const float*)d_in[1];
    const float* conv_b = (const float*)d_in[2];
    const float* dt_w   = (const float*)d_in[3];
    const float* dt_b   = (const float*)d_in[4];
    const float* A      = (const float*)d_in[5];
    const float* D      = (const float*)d_in[6];
    const float* g1w    = (const float*)d_in[7];
    const float* g1b    = (const float*)d_in[8];
    const float* g2w    = (const float*)d_in[9];
    const float* g2b    = (const float*)d_in[10];

    char* ws = (char*)d_ws;
    // layout (xT overlaid by hend/decay after K1's last read of xT)
    unsigned short* xT    = (unsigned short*)(ws + 0);          // 16.78 MB
    float* hend           = (float*)(ws + 0);                   //  8.39 MB (after K1)
    float* decay          = (float*)(ws + 8388608);             //  8.39 MB
    unsigned short* convT = (unsigned short*)(ws + 16777216);   // 16.78 MB
    unsigned short* dtT   = (unsigned short*)(ws + 33554432);   // 16.78 MB
    float* H0             = (float*)(ws + 50331648);            //  8.39 MB
    short* wf             = (short*)(ws + 58720256);            //  294912 B
    short* wdtf           = (short*)(ws + 59015168);            //  32768 B
    float* pooled         = (float*)(ws + 59047936);            //  8192 B
    float* gate           = (float*)(ws + 59056128);            //  8192 B
    float* Antab          = (float*)(ws + 59064320);            //  8192 B
    float* An2tab         = (float*)(ws + 59072512);            //  8192 B
    float* Dp             = (float*)(ws + 59080704);            //  512 B
    float* outp           = (float*)d_out;

    hipLaunchKernelGGL(k0a, dim3(97), dim3(256), 0, stream, conv_w, dt_w, A, D, wf, wdtf, Antab, An2tab, Dp, pooled);
    hipLaunchKernelGGL(k0b, dim3(2048), dim3(256), 0, stream, x, xT);
    hipLaunchKernelGGL(k1, dim3(1024), dim3(256), 0, stream, xT, wf, conv_b, convT, pooled);
    hipLaunchKernelGGL(k2, dim3(16), dim3(128), 0, stream, pooled, g1w, g1b, g2w, g2b, gate);
    hipLaunchKernelGGL(k3, dim3(512), dim3(256), 0, stream, convT, wdtf, gate, dt_b, An2tab, dtT, hend, decay);
    hipLaunchKernelGGL(k5, dim3(128), dim3(256), 0, stream, hend, decay, H0);
    hipLaunchKernelGGL(k6, dim3(1024), dim3(128), 0, stream, convT, dtT, gate, Antab, An2tab, Dp, H0, x, outp);
}

// Round 5
// 129.715 us; speedup vs baseline: 1.2555x; 1.0413x over previous
//
#include <hip/hip_runtime.h>
#include <hip/hip_bf16.h>
#include <stdint.h>

#define BB 16
#define CC 128
#define HH 64
#define WW 64
#define LL 4096
#define SS 16
#define NCH 64
#define CT 64

typedef __attribute__((ext_vector_type(4))) float f32x4;
typedef __attribute__((ext_vector_type(8))) short short8;
typedef __attribute__((ext_vector_type(4))) unsigned int u32x4;

#define AS1 __attribute__((address_space(1)))
#define AS3 __attribute__((address_space(3)))

__device__ __forceinline__ float bf2f(unsigned short u) {
    union { unsigned int i; float f; } v;
    v.i = ((unsigned int)u) << 16;
    return v.f;
}
__device__ __forceinline__ unsigned short f2bf(float f) {
    union { float f; unsigned int i; } v;
    v.f = f;
    unsigned int x = v.i;
    return (unsigned short)((x + 0x7fffu + ((x >> 16) & 1u)) >> 16);
}
__device__ __forceinline__ float fexp2(float x) { return __builtin_amdgcn_exp2f(x); }

// ---------------- K0: x-transpose (blocks 0..2047) + weight transforms (blocks 2048..) ----------------
__global__ __launch_bounds__(256) void k0(const float* __restrict__ x, unsigned short* __restrict__ xT,
                                          const float* __restrict__ conv_w, const float* __restrict__ dt_w,
                                          const float* __restrict__ A, const float* __restrict__ Dv,
                                          const float* __restrict__ g1w, const float* __restrict__ g2w,
                                          short* __restrict__ wf, short* __restrict__ wdtf,
                                          float* __restrict__ An, float* __restrict__ An2, float* __restrict__ Dp,
                                          float* __restrict__ pooled, float* __restrict__ g1wT, float* __restrict__ g2wT) {
    __shared__ float lt[64][65];
    int bid = blockIdx.x;
    int tid = threadIdx.x;
    if (bid < 2048) {
        int b = bid >> 7, rem = bid & 127;
        int tt = rem >> 1, ct = rem & 1;
        int t0 = tt * 64, c0 = ct * 64;
        int colr = tid & 63, rowb = tid >> 6;
#pragma unroll
        for (int r = 0; r < 16; ++r) {
            int row = rowb + r * 4;
            lt[row][colr] = x[(size_t)(b * CC + c0 + row) * LL + t0 + colr];
        }
        __syncthreads();
#pragma unroll
        for (int r = 0; r < 16; ++r) {
            int trow = rowb + r * 4;
            xT[((size_t)b * LL + t0 + trow) * CC + c0 + colr] = f2bf(lt[colr][trow]);
        }
        return;
    }
    int idx = (bid - 2048) * 256 + tid;
    if (idx < 18432) {
        int lane = idx & 63, fr = idx >> 6;
        int nfg = fr & 7, ks = (fr >> 3) & 3, tp = fr >> 5;
        int dy = tp / 3, dx = tp % 3;
        int cout = nfg * 16 + (lane & 15);
        int cin0 = ks * 32 + (lane >> 4) * 8;
        short8 v;
#pragma unroll
        for (int j = 0; j < 8; ++j)
            v[j] = (short)f2bf(conv_w[((cout * CC + cin0 + j) * 3 + dy) * 3 + dx]);
        *(short8*)(wf + (size_t)idx * 8) = v;
    } else if (idx < 20480) {
        int i2 = idx - 18432;
        int lane = i2 & 63, fr = i2 >> 6;
        int nfg = fr & 7, ks = fr >> 3;
        int o = nfg * 16 + (lane & 15);
        int c0 = ks * 32 + (lane >> 4) * 8;
        short8 v;
#pragma unroll
        for (int j = 0; j < 8; ++j) v[j] = (short)f2bf(dt_w[o * CC + c0 + j]);
        *(short8*)(wdtf + (size_t)i2 * 8) = v;
    } else if (idx < 22528) {
        int i3 = idx - 20480;
        float a = -expf(A[i3]);
        An[i3] = a;
        An2[i3] = a * 1.4426950408889634f;
    } else if (idx < 22656) {
        int c = idx - 22528;
        Dp[c] = expf(Dv[c]);
    } else if (idx < 24704) {
        pooled[idx - 22656] = 0.f;
    } else if (idx < 41088) {
        int i = idx - 24704;
        int c = i >> 7, o = i & 127;
        g1wT[i] = g1w[o * 128 + c];
    } else if (idx < 57472) {
        int i = idx - 41088;
        int c = i >> 7, o = i & 127;
        g2wT[i] = g2w[o * 128 + c];
    }
}

// ---------------- K1: 3x3 conv via MFMA implicit GEMM ----------------
__global__ __launch_bounds__(256) void k1(const unsigned short* __restrict__ xT,
                                          const short* __restrict__ wf,
                                          const float* __restrict__ conv_b,
                                          unsigned short* __restrict__ convT,
                                          float* __restrict__ pooled) {
    __shared__ __align__(16) unsigned short slab[3 * 66 * 128];  // 50688 B
    int bid = blockIdx.x;
    int b = bid >> 6, h = bid & 63;
    int tid = threadIdx.x;
    int wave = tid >> 6, lane = tid & 63;

    if (tid < 96) {
        int dy = tid >> 5, r = (tid >> 4) & 1, j = tid & 15;
        u32x4 z = {0, 0, 0, 0};
        *(u32x4*)((char*)slab + dy * 16896 + (r ? 16640 : 0) + j * 16) = z;
    }
#pragma unroll
    for (int dy = 0; dy < 3; ++dy) {
        int hs = h + dy - 1;
        char* slabdy = (char*)slab + dy * 16896;
        if (hs >= 0 && hs < HH) {
            const char* src = (const char*)xT + (size_t)(b * LL + hs * 64) * 256;
#pragma unroll
            for (int i = 0; i < 4; ++i) {
                unsigned int Xbase = 256u + (unsigned)i * 4096u + (unsigned)wave * 1024u;
                unsigned int X = Xbase + (unsigned)lane * 16u;
                unsigned int tok = X >> 8;
                unsigned int srcoff = ((X & ~255u) - 256u) | ((X & 255u) ^ ((tok & 7u) << 4));
                __builtin_amdgcn_global_load_lds((const AS1 unsigned int*)(src + srcoff),
                                                 (AS3 unsigned int*)(slabdy + Xbase), 16, 0, 0);
            }
        } else {
            u32x4 z = {0, 0, 0, 0};
#pragma unroll
            for (int i = 0; i < 4; ++i)
                *(u32x4*)(slabdy + 256 + tid * 64 + i * 16) = z;
        }
    }
    __syncthreads();

    int lm = lane & 15, lg = lane >> 4;
    f32x4 acc[4][2];
#pragma unroll
    for (int m = 0; m < 4; ++m)
#pragma unroll
        for (int n = 0; n < 2; ++n) acc[m][n] = (f32x4){0.f, 0.f, 0.f, 0.f};

#pragma unroll
    for (int tp = 0; tp < 9; ++tp) {
        int dy = tp / 3, dx = tp % 3;
        const char* slabdy = (const char*)slab + dy * 16896;
#pragma unroll
        for (int ks = 0; ks < 4; ++ks) {
            short8 bf0 = *(const short8*)(wf + ((size_t)(((tp * 4 + ks) * 8) + wave * 2 + 0) * 64 + lane) * 8);
            short8 bf1 = *(const short8*)(wf + ((size_t)(((tp * 4 + ks) * 8) + wave * 2 + 1) * 64 + lane) * 8);
#pragma unroll
            for (int mf = 0; mf < 4; ++mf) {
                int tok = mf * 16 + lm + dx;
                unsigned int off = (unsigned)((tok * 256 + ks * 64 + lg * 16) ^ ((tok & 7) << 4));
                short8 af = *(const short8*)(slabdy + off);
                acc[mf][0] = __builtin_amdgcn_mfma_f32_16x16x32_bf16(af, bf0, acc[mf][0], 0, 0, 0);
                acc[mf][1] = __builtin_amdgcn_mfma_f32_16x16x32_bf16(af, bf1, acc[mf][1], 0, 0, 0);
            }
        }
    }

    int n0w = wave * 32;
    size_t tokbase = (size_t)(b * LL + h * 64);
    float psum[2] = {0.f, 0.f};
#pragma unroll
    for (int nf = 0; nf < 2; ++nf) {
        int n = n0w + nf * 16 + lm;
        float bias = conv_b[n];
#pragma unroll
        for (int mf = 0; mf < 4; ++mf)
#pragma unroll
            for (int r = 0; r < 4; ++r) {
                int w = mf * 16 + lg * 4 + r;
                float v = acc[mf][nf][r] + bias;
                convT[(tokbase + w) * CC + n] = f2bf(v);
                psum[nf] += v;
            }
    }
#pragma unroll
    for (int nf = 0; nf < 2; ++nf) {
        float s = psum[nf];
        s += __shfl_xor(s, 16);
        s += __shfl_xor(s, 32);
        if (lane < 16) atomicAdd(&pooled[b * CC + n0w + nf * 16 + lane], s);
    }
}

// ---------------- K3: gate (per-block) + dt GEMM + sigmoid + fused scan phase-1 ----------------
__global__ __launch_bounds__(256) void k3(const unsigned short* __restrict__ convT,
                                          const short* __restrict__ wdtf,
                                          const float* __restrict__ pooled,
                                          const float* __restrict__ g1wT, const float* __restrict__ g1b,
                                          const float* __restrict__ g2wT, const float* __restrict__ g2b,
                                          float* __restrict__ gate,
                                          const float* __restrict__ dt_b,
                                          const float* __restrict__ An2,
                                          unsigned short* __restrict__ dtT,
                                          float* __restrict__ hend, float* __restrict__ decay) {
    __shared__ __align__(16) unsigned short albuf[128 * 128];   // 32KB gated-x (swizzled)
    __shared__ __align__(16) unsigned short dtl[128 * 136];     // 34KB dt (stride-136)
    __shared__ float gl[128];
    float* meanr = (float*)dtl;        // alias: dead before dtl's first real use
    float* garr  = ((float*)dtl) + 128;
    int bid = blockIdx.x;
    int b = bid >> 5, tile = bid & 31, t0 = tile * 128;
    int tid = threadIdx.x;
    int wave = tid >> 6, lane = tid & 63;

    // per-block gate compute (deterministic, identical across tiles of same b)
    if (tid < 128) meanr[tid] = pooled[b * CC + tid] * (1.f / 4096.f);
    __syncthreads();
    if (tid < 128) {
        float acc = g1b[tid];
        for (int c = 0; c < 128; ++c) acc += meanr[c] * g1wT[c * 128 + tid];
        garr[tid] = fmaxf(acc, 0.f);
    }
    __syncthreads();
    if (tid < 128) {
        float acc2 = g2b[tid];
        for (int c = 0; c < 128; ++c) acc2 += garr[c] * g2wT[c * 128 + tid];
        float gv = __builtin_amdgcn_rcpf(1.f + fexp2(-1.4426950408889634f * acc2));
        gl[tid] = gv;
        if (tile == 0) gate[b * CC + tid] = gv;
    }
    __syncthreads();

    const char* srcb = (const char*)convT + (size_t)(b * LL + t0) * 256;
#pragma unroll
    for (int i = 0; i < 8; ++i) {
        unsigned int byteoff = (unsigned)((i * 256 + tid) * 16);
        unsigned int tok = byteoff >> 8;
        unsigned int inner = byteoff & 255u;
        int c8 = (int)(inner >> 1);
        short8 v = *(const short8*)(srcb + (size_t)tok * 256 + inner);
#pragma unroll
        for (int j = 0; j < 8; ++j) {
            float f = bf2f((unsigned short)v[j]) * gl[c8 + j];
            v[j] = (short)f2bf(f);
        }
        *(short8*)((char*)albuf + (byteoff ^ ((tok & 7u) << 4))) = v;
    }
    __syncthreads();

    int lm = lane & 15, lg = lane >> 4;
    f32x4 acc[8][2];
#pragma unroll
    for (int m = 0; m < 8; ++m)
#pragma unroll
        for (int n = 0; n < 2; ++n) acc[m][n] = (f32x4){0.f, 0.f, 0.f, 0.f};
#pragma unroll
    for (int ks = 0; ks < 4; ++ks) {
        short8 bf0 = *(const short8*)(wdtf + ((size_t)((ks * 8) + wave * 2 + 0) * 64 + lane) * 8);
        short8 bf1 = *(const short8*)(wdtf + ((size_t)((ks * 8) + wave * 2 + 1) * 64 + lane) * 8);
#pragma unroll
        for (int mf = 0; mf < 8; ++mf) {
            int tok = mf * 16 + lm;
            unsigned int off = (unsigned)((tok * 256 + ks * 64 + lg * 16) ^ ((tok & 7) << 4));
            short8 af = *(const short8*)((const char*)albuf + off);
            acc[mf][0] = __builtin_amdgcn_mfma_f32_16x16x32_bf16(af, bf0, acc[mf][0], 0, 0, 0);
            acc[mf][1] = __builtin_amdgcn_mfma_f32_16x16x32_bf16(af, bf1, acc[mf][1], 0, 0, 0);
        }
    }
    __syncthreads();   // ensure gate-phase aliased reads of dtl are long done (they are), and albuf reads done
#pragma unroll
    for (int nf = 0; nf < 2; ++nf) {
        int o = wave * 32 + nf * 16 + lm;
        float zb = dt_b[o];
#pragma unroll
        for (int mf = 0; mf < 8; ++mf)
#pragma unroll
            for (int r = 0; r < 4; ++r) {
                int tok = mf * 16 + lg * 4 + r;
                float z = acc[mf][nf][r] + zb;
                float d = __builtin_amdgcn_rcpf(1.f + fexp2(-1.4426950408889634f * z));
                unsigned short ub = f2bf(d);
                dtT[(size_t)(b * LL + t0 + tok) * CC + o] = ub;
                dtl[tok * 136 + o] = ub;
            }
    }
    __syncthreads();

    // fused scan phase-1: 2 chunks x 128 channels; x from albuf (gated), dt from dtl
    int half = tid >> 7, c = tid & 127;
    int ch = tile * 2 + half;
    float a2[SS], h[SS];
#pragma unroll
    for (int s = 0; s < SS; ++s) {
        a2[s] = An2[c * SS + s];
        h[s] = 0.f;
    }
    float sdt = 0.f;
#pragma unroll 4
    for (int t = 0; t < CT; ++t) {
        int tokb = half * 64 + t;
        unsigned int xoff = ((unsigned)(tokb * 256 + c * 2)) ^ (((unsigned)tokb & 7u) << 4);
        float x = bf2f(*(const unsigned short*)((const char*)albuf + xoff));
        float d = bf2f(dtl[tokb * 136 + c]);
        sdt += d;
#pragma unroll
        for (int s = 0; s < SS; ++s) h[s] = h[s] * fexp2(a2[s] * d) + x;
    }
    size_t base = ((size_t)(b * NCH + ch) * CC + c) * SS;
#pragma unroll
    for (int q = 0; q < 4; ++q) {
        f32x4 hv, dv;
#pragma unroll
        for (int j = 0; j < 4; ++j) {
            hv[j] = h[q * 4 + j];
            dv[j] = fexp2(a2[q * 4 + j] * sdt);
        }
        *(f32x4*)(hend + base + q * 4) = hv;
        *(f32x4*)(decay + base + q * 4) = dv;
    }
}

// ---------------- K5: sequential chunk combine ----------------
__global__ __launch_bounds__(256) void k5(const float* __restrict__ hend, const float* __restrict__ decay,
                                          float* __restrict__ H0) {
    int idx = blockIdx.x * 256 + threadIdx.x;  // 32768
    int b = idx >> 11, rem = idx & 2047;
    float Hv = 0.f;
    for (int k = 0; k < NCH; ++k) {
        size_t base = (size_t)(b * NCH + k) * 2048 + rem;
        H0[base] = Hv;
        Hv = hend[base] + Hv * decay[base];
    }
}

// ---------------- K6: scan phase 2, LDS-staged tiles, coalesced output ----------------
__global__ __launch_bounds__(128) void k6(const unsigned short* __restrict__ convT,
                                          const unsigned short* __restrict__ dtT,
                                          const float* __restrict__ gate,
                                          const float* __restrict__ Antab,
                                          const float* __restrict__ An2tab,
                                          const float* __restrict__ Dp,
                                          const float* __restrict__ H0,
                                          const float* __restrict__ xin,
                                          float* __restrict__ out) {
    __shared__ __align__(16) unsigned short xl[64 * 128];   // 16KB
    __shared__ __align__(16) unsigned short dl[64 * 128];   // 16KB
    __shared__ unsigned short ylds[128][66];                // 16.9KB
    int bid = blockIdx.x;
    int b = bid >> 6, ch = bid & 63;
    int tid = threadIdx.x;
    int wave = tid >> 6, lane = tid & 63;
    int t0 = ch * CT;

    // stage convT/dtT tiles (linear, coalesced 16B direct-to-LDS)
    const char* xsrc = (const char*)convT + (size_t)(b * LL + t0) * 256;
    const char* dsrc = (const char*)dtT + (size_t)(b * LL + t0) * 256;
#pragma unroll
    for (int i = 0; i < 8; ++i) {
        unsigned int off = (unsigned)(i * 2048 + wave * 1024);
        __builtin_amdgcn_global_load_lds((const AS1 unsigned int*)(xsrc + off + lane * 16u),
                                         (AS3 unsigned int*)((char*)xl + off), 16, 0, 0);
        __builtin_amdgcn_global_load_lds((const AS1 unsigned int*)(dsrc + off + lane * 16u),
                                         (AS3 unsigned int*)((char*)dl + off), 16, 0, 0);
    }

    int c = tid;
    float a2[SS], an[SS], h[SS];
#pragma unroll
    for (int s = 0; s < SS; ++s) {
        a2[s] = An2tab[c * SS + s];
        an[s] = Antab[c * SS + s];
    }
    size_t hbase = ((size_t)(b * NCH + ch) * CC + c) * SS;
#pragma unroll
    for (int q = 0; q < 4; ++q) {
        f32x4 hv = *(const f32x4*)(H0 + hbase + q * 4);
#pragma unroll
        for (int j = 0; j < 4; ++j) h[q * 4 + j] = hv[j];
    }
    float g = gate[b * CC + c];
    float dpc = Dp[c];
    __syncthreads();   // drains global_load_lds (vmcnt(0) before barrier)

#pragma unroll 4
    for (int t = 0; t < CT; ++t) {
        float x = bf2f(xl[t * 128 + c]) * g;
        float d = bf2f(dl[t * 128 + c]);
        float y = dpc * x;
#pragma unroll
        for (int s = 0; s < SS; ++s) {
            h[s] = h[s] * fexp2(a2[s] * d) + x;
            y += h[s] * an[s];
        }
        ylds[c][t] = f2bf(y);
    }
    __syncthreads();

    // coalesced output: wave lanes sweep 64 contiguous tokens of one channel row
    int tt = lane;
    size_t outbase = (size_t)b * CC * LL + t0 + tt;
#pragma unroll 4
    for (int rr = 0; rr < 64; ++rr) {
        int row = rr * 2 + wave;
        size_t gi = outbase + (size_t)row * LL;
        out[gi] = bf2f(ylds[row][tt]) + xin[gi];
    }
}

extern "C" void kernel_launch(void* const* d_in, const int* in_sizes, int n_in,
                              void* d_out, int out_size, void* d_ws, size_t ws_size,
                              hipStream_t stream) {
    const float* x      = (const float*)d_in[0];
    const float* conv_w = (const float*)d_in[1];
    const float* conv_b = (const float*)d_in[2];
    const float* dt_w   = (const float*)d_in[3];
    const float* dt_b   = (const float*)d_in[4];
    const float* A      = (const float*)d_in[5];
    const float* D      = (const float*)d_in[6];
    const float* g1w    = (const float*)d_in[7];
    const float* g1b    = (const float*)d_in[8];
    const float* g2w    = (const float*)d_in[9];
    const float* g2b    = (const float*)d_in[10];

    char* ws = (char*)d_ws;
    unsigned short* xT    = (unsigned short*)(ws + 0);          // 16.78 MB (k0->k1)
    float* hend           = (float*)(ws + 0);                   //  8.39 MB (after k1, overlays xT)
    float* decay          = (float*)(ws + 8388608);             //  8.39 MB
    unsigned short* convT = (unsigned short*)(ws + 16777216);   // 16.78 MB
    unsigned short* dtT   = (unsigned short*)(ws + 33554432);   // 16.78 MB
    float* H0             = (float*)(ws + 50331648);            //  8.39 MB (written by k5)
    float* g1wT           = (float*)(ws + 50331648);            //  64 KB (k0->k3; overlaid by H0 after k3)
    float* g2wT           = (float*)(ws + 50397184);            //  64 KB (k0->k3; overlaid by H0 after k3)
    short* wf             = (short*)(ws + 58720256);            //  294912 B
    short* wdtf           = (short*)(ws + 59015168);            //  32768 B
    float* pooled         = (float*)(ws + 59047936);            //  8192 B
    float* gate           = (float*)(ws + 59056128);            //  8192 B
    float* Antab          = (float*)(ws + 59064320);            //  8192 B
    float* An2tab         = (float*)(ws + 59072512);            //  8192 B
    float* Dp             = (float*)(ws + 59080704);            //  512 B
    float* outp           = (float*)d_out;

    hipLaunchKernelGGL(k0, dim3(2273), dim3(256), 0, stream, x, xT, conv_w, dt_w, A, D, g1w, g2w,
                       wf, wdtf, Antab, An2tab, Dp, pooled, g1wT, g2wT);
    hipLaunchKernelGGL(k1, dim3(1024), dim3(256), 0, stream, xT, wf, conv_b, convT, pooled);
    hipLaunchKernelGGL(k3, dim3(512), dim3(256), 0, stream, convT, wdtf, pooled, g1wT, g1b, g2wT, g2b,
                       gate, dt_b, An2tab, dtT, hend, decay);
    hipLaunchKernelGGL(k5, dim3(128), dim3(256), 0, stream, hend, decay, H0);
    hipLaunchKernelGGL(k6, dim3(1024), dim3(128), 0, stream, convT, dtT, gate, Antab, An2tab, Dp, H0, x, outp);
}

// Round 6
// 120.718 us; speedup vs baseline: 1.3491x; 1.0745x over previous
//
#include <hip/hip_runtime.h>
#include <hip/hip_bf16.h>
#include <stdint.h>

#define BB 16
#define CC 128
#define HH 64
#define WW 64
#define LL 4096
#define SS 16
#define NCH 64
#define CT 64

typedef __attribute__((ext_vector_type(4))) float f32x4;
typedef __attribute__((ext_vector_type(8))) short short8;
typedef __attribute__((ext_vector_type(4))) unsigned int u32x4;

#define AS1 __attribute__((address_space(1)))
#define AS3 __attribute__((address_space(3)))

__device__ __forceinline__ float bf2f(unsigned short u) {
    union { unsigned int i; float f; } v;
    v.i = ((unsigned int)u) << 16;
    return v.f;
}
__device__ __forceinline__ unsigned short f2bf(float f) {
    union { float f; unsigned int i; } v;
    v.f = f;
    unsigned int x = v.i;
    return (unsigned short)((x + 0x7fffu + ((x >> 16) & 1u)) >> 16);
}
__device__ __forceinline__ float fexp2(float x) { return __builtin_amdgcn_exp2f(x); }

// ---------------- K0: x-transpose (blocks 0..2047) + weight transforms (blocks 2048..) ----------------
__global__ __launch_bounds__(256) void k0(const float* __restrict__ x, unsigned short* __restrict__ xT,
                                          const float* __restrict__ conv_w, const float* __restrict__ dt_w,
                                          const float* __restrict__ A, const float* __restrict__ Dv,
                                          const float* __restrict__ g1w, const float* __restrict__ g2w,
                                          short* __restrict__ wf, short* __restrict__ wdtf,
                                          float* __restrict__ An, float* __restrict__ An2, float* __restrict__ Dp,
                                          float* __restrict__ pooled, float* __restrict__ g1wT, float* __restrict__ g2wT) {
    __shared__ float lt[64][65];
    int bid = blockIdx.x;
    int tid = threadIdx.x;
    if (bid < 2048) {
        int b = bid >> 7, rem = bid & 127;
        int tt = rem >> 1, ct = rem & 1;
        int t0 = tt * 64, c0 = ct * 64;
        int colr = tid & 63, rowb = tid >> 6;
#pragma unroll
        for (int r = 0; r < 16; ++r) {
            int row = rowb + r * 4;
            lt[row][colr] = x[(size_t)(b * CC + c0 + row) * LL + t0 + colr];
        }
        __syncthreads();
#pragma unroll
        for (int r = 0; r < 16; ++r) {
            int trow = rowb + r * 4;
            xT[((size_t)b * LL + t0 + trow) * CC + c0 + colr] = f2bf(lt[colr][trow]);
        }
        return;
    }
    int idx = (bid - 2048) * 256 + tid;
    if (idx < 18432) {
        int lane = idx & 63, fr = idx >> 6;
        int nfg = fr & 7, ks = (fr >> 3) & 3, tp = fr >> 5;
        int dy = tp / 3, dx = tp % 3;
        int cout = nfg * 16 + (lane & 15);
        int cin0 = ks * 32 + (lane >> 4) * 8;
        short8 v;
#pragma unroll
        for (int j = 0; j < 8; ++j)
            v[j] = (short)f2bf(conv_w[((cout * CC + cin0 + j) * 3 + dy) * 3 + dx]);
        *(short8*)(wf + (size_t)idx * 8) = v;
    } else if (idx < 20480) {
        int i2 = idx - 18432;
        int lane = i2 & 63, fr = i2 >> 6;
        int nfg = fr & 7, ks = fr >> 3;
        int o = nfg * 16 + (lane & 15);
        int c0 = ks * 32 + (lane >> 4) * 8;
        short8 v;
#pragma unroll
        for (int j = 0; j < 8; ++j) v[j] = (short)f2bf(dt_w[o * CC + c0 + j]);
        *(short8*)(wdtf + (size_t)i2 * 8) = v;
    } else if (idx < 22528) {
        int i3 = idx - 20480;
        float a = -expf(A[i3]);
        An[i3] = a;
        An2[i3] = a * 1.4426950408889634f;
    } else if (idx < 22656) {
        int c = idx - 22528;
        Dp[c] = expf(Dv[c]);
    } else if (idx < 24704) {
        pooled[idx - 22656] = 0.f;
    } else if (idx < 41088) {
        int i = idx - 24704;
        int c = i >> 7, o = i & 127;
        g1wT[i] = g1w[o * 128 + c];
    } else if (idx < 57472) {
        int i = idx - 41088;
        int c = i >> 7, o = i & 127;
        g2wT[i] = g2w[o * 128 + c];
    }
}

// ---------------- K1: 3x3 conv via MFMA implicit GEMM ----------------
__global__ __launch_bounds__(256) void k1(const unsigned short* __restrict__ xT,
                                          const short* __restrict__ wf,
                                          const float* __restrict__ conv_b,
                                          unsigned short* __restrict__ convT,
                                          float* __restrict__ pooled) {
    __shared__ __align__(16) unsigned short slab[3 * 66 * 128];  // 50688 B
    int bid = blockIdx.x;
    int b = bid >> 6, h = bid & 63;
    int tid = threadIdx.x;
    int wave = tid >> 6, lane = tid & 63;

    if (tid < 96) {
        int dy = tid >> 5, r = (tid >> 4) & 1, j = tid & 15;
        u32x4 z = {0, 0, 0, 0};
        *(u32x4*)((char*)slab + dy * 16896 + (r ? 16640 : 0) + j * 16) = z;
    }
#pragma unroll
    for (int dy = 0; dy < 3; ++dy) {
        int hs = h + dy - 1;
        char* slabdy = (char*)slab + dy * 16896;
        if (hs >= 0 && hs < HH) {
            const char* src = (const char*)xT + (size_t)(b * LL + hs * 64) * 256;
#pragma unroll
            for (int i = 0; i < 4; ++i) {
                unsigned int Xbase = 256u + (unsigned)i * 4096u + (unsigned)wave * 1024u;
                unsigned int X = Xbase + (unsigned)lane * 16u;
                unsigned int tok = X >> 8;
                unsigned int srcoff = ((X & ~255u) - 256u) | ((X & 255u) ^ ((tok & 7u) << 4));
                __builtin_amdgcn_global_load_lds((const AS1 unsigned int*)(src + srcoff),
                                                 (AS3 unsigned int*)(slabdy + Xbase), 16, 0, 0);
            }
        } else {
            u32x4 z = {0, 0, 0, 0};
#pragma unroll
            for (int i = 0; i < 4; ++i)
                *(u32x4*)(slabdy + 256 + tid * 64 + i * 16) = z;
        }
    }
    __syncthreads();

    int lm = lane & 15, lg = lane >> 4;
    f32x4 acc[4][2];
#pragma unroll
    for (int m = 0; m < 4; ++m)
#pragma unroll
        for (int n = 0; n < 2; ++n) acc[m][n] = (f32x4){0.f, 0.f, 0.f, 0.f};

#pragma unroll
    for (int tp = 0; tp < 9; ++tp) {
        int dy = tp / 3, dx = tp % 3;
        const char* slabdy = (const char*)slab + dy * 16896;
#pragma unroll
        for (int ks = 0; ks < 4; ++ks) {
            short8 bf0 = *(const short8*)(wf + ((size_t)(((tp * 4 + ks) * 8) + wave * 2 + 0) * 64 + lane) * 8);
            short8 bf1 = *(const short8*)(wf + ((size_t)(((tp * 4 + ks) * 8) + wave * 2 + 1) * 64 + lane) * 8);
#pragma unroll
            for (int mf = 0; mf < 4; ++mf) {
                int tok = mf * 16 + lm + dx;
                unsigned int off = (unsigned)((tok * 256 + ks * 64 + lg * 16) ^ ((tok & 7) << 4));
                short8 af = *(const short8*)(slabdy + off);
                acc[mf][0] = __builtin_amdgcn_mfma_f32_16x16x32_bf16(af, bf0, acc[mf][0], 0, 0, 0);
                acc[mf][1] = __builtin_amdgcn_mfma_f32_16x16x32_bf16(af, bf1, acc[mf][1], 0, 0, 0);
            }
        }
    }

    int n0w = wave * 32;
    size_t tokbase = (size_t)(b * LL + h * 64);
    float psum[2] = {0.f, 0.f};
#pragma unroll
    for (int nf = 0; nf < 2; ++nf) {
        int n = n0w + nf * 16 + lm;
        float bias = conv_b[n];
#pragma unroll
        for (int mf = 0; mf < 4; ++mf)
#pragma unroll
            for (int r = 0; r < 4; ++r) {
                int w = mf * 16 + lg * 4 + r;
                float v = acc[mf][nf][r] + bias;
                convT[(tokbase + w) * CC + n] = f2bf(v);
                psum[nf] += v;
            }
    }
#pragma unroll
    for (int nf = 0; nf < 2; ++nf) {
        float s = psum[nf];
        s += __shfl_xor(s, 16);
        s += __shfl_xor(s, 32);
        if (lane < 16) atomicAdd(&pooled[b * CC + n0w + nf * 16 + lane], s);
    }
}

// ---------------- K3: gate (per-block) + dt GEMM + sigmoid + fused scan phase-1 ----------------
__global__ __launch_bounds__(256) void k3(const unsigned short* __restrict__ convT,
                                          const short* __restrict__ wdtf,
                                          const float* __restrict__ pooled,
                                          const float* __restrict__ g1wT, const float* __restrict__ g1b,
                                          const float* __restrict__ g2wT, const float* __restrict__ g2b,
                                          float* __restrict__ gate,
                                          const float* __restrict__ dt_b,
                                          const float* __restrict__ An2,
                                          unsigned short* __restrict__ dtT,
                                          float* __restrict__ hend, float* __restrict__ decay) {
    __shared__ __align__(16) unsigned short albuf[128 * 128];   // 32KB gated-x (swizzled)
    __shared__ __align__(16) unsigned short dtl[128 * 136];     // 34KB dt (stride-136)
    __shared__ float gl[128];
    float* meanr = (float*)dtl;        // alias: dead before dtl's first real use
    float* garr  = ((float*)dtl) + 128;
    int bid = blockIdx.x;
    int b = bid >> 5, tile = bid & 31, t0 = tile * 128;
    int tid = threadIdx.x;
    int wave = tid >> 6, lane = tid & 63;

    // per-block gate compute (deterministic, identical across tiles of same b)
    if (tid < 128) meanr[tid] = pooled[b * CC + tid] * (1.f / 4096.f);
    __syncthreads();
    if (tid < 128) {
        float acc = g1b[tid];
        for (int c = 0; c < 128; ++c) acc += meanr[c] * g1wT[c * 128 + tid];
        garr[tid] = fmaxf(acc, 0.f);
    }
    __syncthreads();
    if (tid < 128) {
        float acc2 = g2b[tid];
        for (int c = 0; c < 128; ++c) acc2 += garr[c] * g2wT[c * 128 + tid];
        float gv = __builtin_amdgcn_rcpf(1.f + fexp2(-1.4426950408889634f * acc2));
        gl[tid] = gv;
        if (tile == 0) gate[b * CC + tid] = gv;
    }
    __syncthreads();

    const char* srcb = (const char*)convT + (size_t)(b * LL + t0) * 256;
#pragma unroll
    for (int i = 0; i < 8; ++i) {
        unsigned int byteoff = (unsigned)((i * 256 + tid) * 16);
        unsigned int tok = byteoff >> 8;
        unsigned int inner = byteoff & 255u;
        int c8 = (int)(inner >> 1);
        short8 v = *(const short8*)(srcb + (size_t)tok * 256 + inner);
#pragma unroll
        for (int j = 0; j < 8; ++j) {
            float f = bf2f((unsigned short)v[j]) * gl[c8 + j];
            v[j] = (short)f2bf(f);
        }
        *(short8*)((char*)albuf + (byteoff ^ ((tok & 7u) << 4))) = v;
    }
    __syncthreads();

    int lm = lane & 15, lg = lane >> 4;
    f32x4 acc[8][2];
#pragma unroll
    for (int m = 0; m < 8; ++m)
#pragma unroll
        for (int n = 0; n < 2; ++n) acc[m][n] = (f32x4){0.f, 0.f, 0.f, 0.f};
#pragma unroll
    for (int ks = 0; ks < 4; ++ks) {
        short8 bf0 = *(const short8*)(wdtf + ((size_t)((ks * 8) + wave * 2 + 0) * 64 + lane) * 8);
        short8 bf1 = *(const short8*)(wdtf + ((size_t)((ks * 8) + wave * 2 + 1) * 64 + lane) * 8);
#pragma unroll
        for (int mf = 0; mf < 8; ++mf) {
            int tok = mf * 16 + lm;
            unsigned int off = (unsigned)((tok * 256 + ks * 64 + lg * 16) ^ ((tok & 7) << 4));
            short8 af = *(const short8*)((const char*)albuf + off);
            acc[mf][0] = __builtin_amdgcn_mfma_f32_16x16x32_bf16(af, bf0, acc[mf][0], 0, 0, 0);
            acc[mf][1] = __builtin_amdgcn_mfma_f32_16x16x32_bf16(af, bf1, acc[mf][1], 0, 0, 0);
        }
    }
    __syncthreads();
#pragma unroll
    for (int nf = 0; nf < 2; ++nf) {
        int o = wave * 32 + nf * 16 + lm;
        float zb = dt_b[o];
#pragma unroll
        for (int mf = 0; mf < 8; ++mf)
#pragma unroll
            for (int r = 0; r < 4; ++r) {
                int tok = mf * 16 + lg * 4 + r;
                float z = acc[mf][nf][r] + zb;
                float d = __builtin_amdgcn_rcpf(1.f + fexp2(-1.4426950408889634f * z));
                unsigned short ub = f2bf(d);
                dtT[(size_t)(b * LL + t0 + tok) * CC + o] = ub;
                dtl[tok * 136 + o] = ub;
            }
    }
    __syncthreads();

    // fused scan phase-1: 2 chunks x 128 channels; x from albuf (gated), dt from dtl
    int half = tid >> 7, c = tid & 127;
    int ch = tile * 2 + half;
    float a2[SS], h[SS];
#pragma unroll
    for (int s = 0; s < SS; ++s) {
        a2[s] = An2[c * SS + s];
        h[s] = 0.f;
    }
    float sdt = 0.f;
#pragma unroll 4
    for (int t = 0; t < CT; ++t) {
        int tokb = half * 64 + t;
        unsigned int xoff = ((unsigned)(tokb * 256 + c * 2)) ^ (((unsigned)tokb & 7u) << 4);
        float x = bf2f(*(const unsigned short*)((const char*)albuf + xoff));
        float d = bf2f(dtl[tokb * 136 + c]);
        sdt += d;
#pragma unroll
        for (int s = 0; s < SS; ++s) h[s] = h[s] * fexp2(a2[s] * d) + x;
    }
    size_t base = ((size_t)(b * NCH + ch) * CC + c) * SS;
#pragma unroll
    for (int q = 0; q < 4; ++q) {
        f32x4 hv, dv;
#pragma unroll
        for (int j = 0; j < 4; ++j) {
            hv[j] = h[q * 4 + j];
            dv[j] = fexp2(a2[q * 4 + j] * sdt);
        }
        *(f32x4*)(hend + base + q * 4) = hv;
        *(f32x4*)(decay + base + q * 4) = dv;
    }
}

// ---------------- K5: sequential chunk combine ----------------
__global__ __launch_bounds__(256) void k5(const float* __restrict__ hend, const float* __restrict__ decay,
                                          float* __restrict__ H0) {
    int idx = blockIdx.x * 256 + threadIdx.x;  // 32768
    int b = idx >> 11, rem = idx & 2047;
    float Hv = 0.f;
    for (int k = 0; k < NCH; ++k) {
        size_t base = (size_t)(b * NCH + k) * 2048 + rem;
        H0[base] = Hv;
        Hv = hend[base] + Hv * decay[base];
    }
}

// ---------------- K6: scan phase 2, direct global reads, split-y, coalesced output ----------------
__global__ __launch_bounds__(128, 4) void k6(const unsigned short* __restrict__ convT,
                                             const unsigned short* __restrict__ dtT,
                                             const float* __restrict__ gate,
                                             const float* __restrict__ Antab,
                                             const float* __restrict__ An2tab,
                                             const float* __restrict__ Dp,
                                             const float* __restrict__ H0,
                                             const float* __restrict__ xin,
                                             float* __restrict__ out) {
    __shared__ unsigned short ylds[128][66];                // 16.9KB only
    int bid = blockIdx.x;
    int b = bid >> 6, ch = bid & 63;
    int tid = threadIdx.x;
    int wave = tid >> 6, lane = tid & 63;
    int t0 = ch * CT;
    int c = tid;

    float a2[SS], an[SS], h[SS];
#pragma unroll
    for (int q = 0; q < 4; ++q) {
        f32x4 av = *(const f32x4*)(An2tab + c * SS + q * 4);
        f32x4 nv = *(const f32x4*)(Antab + c * SS + q * 4);
#pragma unroll
        for (int j = 0; j < 4; ++j) { a2[q * 4 + j] = av[j]; an[q * 4 + j] = nv[j]; }
    }
    size_t hbase = ((size_t)(b * NCH + ch) * CC + c) * SS;
#pragma unroll
    for (int q = 0; q < 4; ++q) {
        f32x4 hv = *(const f32x4*)(H0 + hbase + q * 4);
#pragma unroll
        for (int j = 0; j < 4; ++j) h[q * 4 + j] = hv[j];
    }
    float g = gate[b * CC + c];
    float dpc = Dp[c];
    const unsigned short* xp = convT + (size_t)(b * LL + t0) * CC + c;
    const unsigned short* dp = dtT + (size_t)(b * LL + t0) * CC + c;

#pragma unroll 4
    for (int t = 0; t < CT; ++t) {
        float x = bf2f(xp[t * CC]) * g;
        float d = bf2f(dp[t * CC]);
        float ys[4];
#pragma unroll
        for (int j = 0; j < 4; ++j) ys[j] = 0.f;
#pragma unroll
        for (int s = 0; s < SS; ++s) {
            h[s] = h[s] * fexp2(a2[s] * d) + x;
            ys[s & 3] += h[s] * an[s];
        }
        float y = dpc * x + ((ys[0] + ys[1]) + (ys[2] + ys[3]));
        ylds[c][t] = f2bf(y);
    }
    __syncthreads();

    // coalesced output: wave lanes sweep 64 contiguous tokens of one channel row
    int tt = lane;
    size_t outbase = (size_t)b * CC * LL + t0 + tt;
#pragma unroll 4
    for (int rr = 0; rr < 64; ++rr) {
        int row = rr * 2 + wave;
        size_t gi = outbase + (size_t)row * LL;
        out[gi] = bf2f(ylds[row][tt]) + xin[gi];
    }
}

extern "C" void kernel_launch(void* const* d_in, const int* in_sizes, int n_in,
                              void* d_out, int out_size, void* d_ws, size_t ws_size,
                              hipStream_t stream) {
    const float* x      = (const float*)d_in[0];
    const float* conv_w = (const float*)d_in[1];
    const float* conv_b = (const float*)d_in[2];
    const float* dt_w   = (const float*)d_in[3];
    const float* dt_b   = (const float*)d_in[4];
    const float* A      = (const float*)d_in[5];
    const float* D      = (const float*)d_in[6];
    const float* g1w    = (const float*)d_in[7];
    const float* g1b    = (const float*)d_in[8];
    const float* g2w    = (const float*)d_in[9];
    const float* g2b    = (const float*)d_in[10];

    char* ws = (char*)d_ws;
    unsigned short* xT    = (unsigned short*)(ws + 0);          // 16.78 MB (k0->k1)
    float* hend           = (float*)(ws + 0);                   //  8.39 MB (after k1, overlays xT)
    float* decay          = (float*)(ws + 8388608);             //  8.39 MB
    unsigned short* convT = (unsigned short*)(ws + 16777216);   // 16.78 MB
    unsigned short* dtT   = (unsigned short*)(ws + 33554432);   // 16.78 MB
    float* H0             = (float*)(ws + 50331648);            //  8.39 MB (written by k5)
    float* g1wT           = (float*)(ws + 50331648);            //  64 KB (k0->k3; overlaid by H0 after k3)
    float* g2wT           = (float*)(ws + 50397184);            //  64 KB (k0->k3; overlaid by H0 after k3)
    short* wf             = (short*)(ws + 58720256);            //  294912 B
    short* wdtf           = (short*)(ws + 59015168);            //  32768 B
    float* pooled         = (float*)(ws + 59047936);            //  8192 B
    float* gate           = (float*)(ws + 59056128);            //  8192 B
    float* Antab          = (float*)(ws + 59064320);            //  8192 B
    float* An2tab         = (float*)(ws + 59072512);            //  8192 B
    float* Dp             = (float*)(ws + 59080704);            //  512 B
    float* outp           = (float*)d_out;

    hipLaunchKernelGGL(k0, dim3(2273), dim3(256), 0, stream, x, xT, conv_w, dt_w, A, D, g1w, g2w,
                       wf, wdtf, Antab, An2tab, Dp, pooled, g1wT, g2wT);
    hipLaunchKernelGGL(k1, dim3(1024), dim3(256), 0, stream, xT, wf, conv_b, convT, pooled);
    hipLaunchKernelGGL(k3, dim3(512), dim3(256), 0, stream, convT, wdtf, pooled, g1wT, g1b, g2wT, g2b,
                       gate, dt_b, An2tab, dtT, hend, decay);
    hipLaunchKernelGGL(k5, dim3(128), dim3(256), 0, stream, hend, decay, H0);
    hipLaunchKernelGGL(k6, dim3(1024), dim3(128), 0, stream, convT, dtT, gate, Antab, An2tab, Dp, H0, x, outp);
}